// Round 9
// baseline (371.899 us; speedup 1.0000x reference)
//
#include <hip/hip_runtime.h>

typedef unsigned int u32;

#define HW 262144   // 512*512
#define W512 512

__device__ __forceinline__ u32 f2b_rtne(float f) {   // f32 -> bf16 bits (RTNE)
    union { float f; u32 i; } c; c.f = f;
    u32 u = c.i;
    return (u + 0x7FFFu + ((u >> 16) & 1u)) >> 16;
}
__device__ __forceinline__ float lo16(u32 w) {
    union { u32 i; float f; } c; c.i = w << 16; return c.f;
}
__device__ __forceinline__ float hi16(u32 w) {
    union { u32 i; float f; } c; c.i = w & 0xFFFF0000u; return c.f;
}

// ---------------------------------------------------------------------------
// k_band: metrics over a horizontal band. nb bands/batch (32 fast, 1 slow).
// ---------------------------------------------------------------------------
__global__ __launch_bounds__(1024) void k_band(
    const float* __restrict__ ev, const float* __restrict__ fr,
    int nb, float* __restrict__ partials, float* __restrict__ z)
{
    __shared__ float sY[18][512];
    __shared__ float sE[18][512];
    __shared__ float cellPart[1024];
    __shared__ float cellFull[256];
    __shared__ float red[16][8];

    int blk = blockIdx.x;
    int b = blk / nb, band = blk % nb;
    int rowsPerBand = 512 / nb;
    int chunks = rowsPerBand >> 4;
    int rBase = band * rowsPerBand;
    int tid = threadIdx.x;

    const float* Pp = ev + (size_t)(b * 2)     * HW;
    const float* Np = ev + (size_t)(b * 2 + 1) * HW;
    const float* Rp = fr + (size_t)(b * 3)     * HW;
    const float* Gp = fr + (size_t)(b * 3 + 1) * HW;
    const float* Bp = fr + (size_t)(b * 3 + 2) * HW;

    if (nb == 1 && tid < 256) cellFull[tid] = 0.f;

    float aY = 0, aY2 = 0, aL = 0, aL2 = 0, aG = 0, aPb = 0, aLE = 0, aLE2 = 0;

    for (int ch = 0; ch < chunks; ++ch) {
        int r0 = rBase + ch * 16;
        for (int idx = tid; idx < 18 * 512; idx += 1024) {
            int rl = idx >> 9, c = idx & 511;
            int gy = r0 - 1 + rl;
            float y = 0.f, e = 0.f;
            if (gy >= 0 && gy < W512) {
                size_t o = (size_t)gy * W512 + c;
                float rr = Rp[o], gg = Gp[o], bb = Bp[o];
                y = fminf(fmaxf(0.299f * rr + 0.587f * gg + 0.114f * bb, 0.f), 1.f);
                e = fmaxf((Pp[o] + Np[o]) * (1.f / 255.f), 0.f);
            }
            sY[rl][c] = y; sE[rl][c] = e;
        }
        __syncthreads();

        float ce = 0.f;
        int hf = tid >> 9, col = tid & 511;
        for (int i = 0; i < 8; ++i) {
            int rl = hf + 2 * i;
            int lr = rl + 1;
            int gy = r0 + rl;
            float y   = sY[lr][col];
            float yu  = sY[lr - 1][col], yd = sY[lr + 1][col];
            float yl  = col        ? sY[lr][col - 1]     : 0.f;
            float yr  = col < 511  ? sY[lr][col + 1]     : 0.f;
            float yul = col        ? sY[lr - 1][col - 1] : 0.f;
            float yur = col < 511  ? sY[lr - 1][col + 1] : 0.f;
            float ydl = col        ? sY[lr + 1][col - 1] : 0.f;
            float ydr = col < 511  ? sY[lr + 1][col + 1] : 0.f;
            float lap = yu + yd + yl + yr - 4.f * y;
            float gx  = (yur + 2.f * yr + ydr) - (yul + 2.f * yl + ydl);
            float gy2 = (ydl + 2.f * yd + ydr) - (yul + 2.f * yu + yur);
            float gm  = sqrtf(gx * gx + gy2 * gy2);
            float e   = sE[lr][col];
            float el  = col       ? sE[lr][col - 1] : 0.f;
            float er  = col < 511 ? sE[lr][col + 1] : 0.f;
            float lapE = sE[lr - 1][col] + sE[lr + 1][col] + el + er - 4.f * e;
            size_t o = (size_t)gy * W512 + col;
            float pn = Pp[o] * (1.f / 255.f);
            float nn = Np[o] * (1.f / 255.f);
            float pb = (pn - nn) / (pn + nn + 1e-12f);
            aY += y; aY2 += y * y; aL += lap; aL2 += lap * lap; aG += gm;
            aPb += pb; aLE += lapE; aLE2 += lapE * lapE; ce += e;
        }
        cellPart[tid] = ce;
        __syncthreads();
        if (tid < 16) {
            float s = 0.f;
            int c0 = tid * 32;
            for (int h2 = 0; h2 < 2; ++h2)
                for (int c = 0; c < 32; ++c) s += cellPart[h2 * 512 + c0 + c];
            if (nb == 1) cellFull[(r0 >> 5) * 16 + tid] += s;
            else         partials[(size_t)blk * 32 + 9 + tid] = s;
        }
        __syncthreads();
    }

    float v[8] = {aY, aY2, aL, aL2, aG, aPb, aLE, aLE2};
    #pragma unroll
    for (int off = 32; off; off >>= 1)
        #pragma unroll
        for (int k = 0; k < 8; ++k) v[k] += __shfl_down(v[k], off);
    int lane = tid & 63, wid = tid >> 6;
    if (lane == 0)
        for (int k = 0; k < 8; ++k) red[wid][k] = v[k];
    __syncthreads();

    if (tid == 0) {
        float s[8];
        for (int k = 0; k < 8; ++k) {
            float t = 0.f;
            for (int w = 0; w < 16; ++w) t += red[w][k];
            s[k] = t;
        }
        if (nb > 1) {
            float* rec = partials + (size_t)blk * 32;
            for (int k = 0; k < 8; ++k) rec[k] = s[k];
        } else {
            float c1 = 0.f, c2 = 0.f, ct = 0.f;
            for (int j = 0; j < 256; ++j) {
                float m = cellFull[j] * (1.f / 1024.f);
                c1 += m; c2 += m * m; ct += cellFull[j];
            }
            const float FN = 262144.f;
            float muY   = s[0] / FN;
            float stdY  = sqrtf(fmaxf(s[1] / FN - muY * muY, 0.f));
            float varlp = fmaxf(s[3] - s[2] * s[2] / FN, 0.f) / (FN - 1.f);
            float gmean = s[4] / FN;
            float mc = c1 * (1.f / 256.f);
            float vc = fmaxf(c2 * (1.f / 256.f) - mc * mc, 0.f);
            float cv = sqrtf(vc) / (mc + 1e-12f);
            float dens = ct / FN;
            float pb = s[5] / FN;
            float varlpE = fmaxf(s[7] - s[6] * s[6] / FN, 0.f) / (FN - 1.f);
            float* zb = z + b * 8;
            zb[0] = muY; zb[1] = stdY; zb[2] = varlp; zb[3] = gmean;
            zb[4] = cv;  zb[5] = dens; zb[6] = pb;    zb[7] = varlpE;
        }
    }
}

// ---------------------------------------------------------------------------
// k_finalize (fast path): merge 32 band records per batch -> z[16][8]
// ---------------------------------------------------------------------------
__global__ __launch_bounds__(256) void k_finalize(
    const float* __restrict__ partials, float* __restrict__ z)
{
    __shared__ float sred[8];
    __shared__ float rr[4][3];
    int b = blockIdx.x, tid = threadIdx.x;
    if (tid < 8) {
        float s = 0.f;
        for (int band = 0; band < 32; ++band)
            s += partials[(size_t)(b * 32 + band) * 32 + tid];
        sred[tid] = s;
    }
    int cr = tid >> 4, cc = tid & 15;
    float cell = partials[(size_t)(b * 32 + 2 * cr)     * 32 + 9 + cc]
               + partials[(size_t)(b * 32 + 2 * cr + 1) * 32 + 9 + cc];
    float m = cell * (1.f / 1024.f);
    float c1 = m, c2 = m * m, ct = cell;
    #pragma unroll
    for (int off = 32; off; off >>= 1) {
        c1 += __shfl_down(c1, off);
        c2 += __shfl_down(c2, off);
        ct += __shfl_down(ct, off);
    }
    int lane = tid & 63, wid = tid >> 6;
    if (lane == 0) { rr[wid][0] = c1; rr[wid][1] = c2; rr[wid][2] = ct; }
    __syncthreads();
    if (tid == 0) {
        float C1 = rr[0][0] + rr[1][0] + rr[2][0] + rr[3][0];
        float C2 = rr[0][1] + rr[1][1] + rr[2][1] + rr[3][1];
        float CT = rr[0][2] + rr[1][2] + rr[2][2] + rr[3][2];
        const float FN = 262144.f;
        float muY   = sred[0] / FN;
        float stdY  = sqrtf(fmaxf(sred[1] / FN - muY * muY, 0.f));
        float varlp = fmaxf(sred[3] - sred[2] * sred[2] / FN, 0.f) / (FN - 1.f);
        float gmean = sred[4] / FN;
        float mc = C1 * (1.f / 256.f);
        float vc = fmaxf(C2 * (1.f / 256.f) - mc * mc, 0.f);
        float cv = sqrtf(vc) / (mc + 1e-12f);
        float dens = CT / FN;
        float pb = sred[5] / FN;
        float varlpE = fmaxf(sred[7] - sred[6] * sred[6] / FN, 0.f) / (FN - 1.f);
        float* zb = z + b * 8;
        zb[0] = muY; zb[1] = stdY; zb[2] = varlp; zb[3] = gmean;
        zb[4] = cv;  zb[5] = dens; zb[6] = pb;    zb[7] = varlpE;
    }
}

// ---------------------------------------------------------------------------
// k_mlp: metrics MLP -> coefs  +  BN-fold weights into global ws buffers
// ---------------------------------------------------------------------------
__global__ __launch_bounds__(1024) void k_mlp(
    const float* __restrict__ z,
    const float* __restrict__ w1, const float* __restrict__ b1,
    const float* __restrict__ w2, const float* __restrict__ b2,
    const float* __restrict__ hgw, const float* __restrict__ hgb,
    const float* __restrict__ hfw, const float* __restrict__ hfb,
    const float* __restrict__ rs,
    const float* __restrict__ c1w,
    const float* __restrict__ bn1g, const float* __restrict__ bn1b,
    const float* __restrict__ bn1m, const float* __restrict__ bn1v,
    const float* __restrict__ c2w,
    const float* __restrict__ bn2g, const float* __restrict__ bn2b,
    const float* __restrict__ bn2m, const float* __restrict__ bn2v,
    float* __restrict__ coefA, float* __restrict__ coefB,
    float* __restrict__ w1f, float* __restrict__ b1f,
    float* __restrict__ w2f, float* __restrict__ b2f)
{
    int j = threadIdx.x, b = threadIdx.y;
    int ft = b * 64 + j;   // flat 0..1023

    if (ft < 720) {        // w1f[tap][oc16]
        int tap = ft >> 4, oc = ft & 15;
        float inv = bn1g[oc] * rsqrtf(bn1v[oc] + 1e-5f);
        w1f[ft] = c1w[oc * 45 + tap] * inv;
    }
    for (int t = ft; t < 1152; t += 1024) {   // w2f[tap144][oc8] (oc>=5 zero pad)
        int tap = t >> 3, oc = t & 7;
        float v = 0.f;
        if (oc < 5) {
            float inv = bn2g[oc] * rsqrtf(bn2v[oc] + 1e-5f);
            v = c2w[oc * 144 + tap] * inv;
        }
        w2f[t] = v;
    }
    if (ft < 16) {
        float inv = bn1g[ft] * rsqrtf(bn1v[ft] + 1e-5f);
        b1f[ft] = bn1b[ft] - bn1m[ft] * inv;
    }
    if (ft >= 32 && ft < 37) {
        int oc = ft - 32;
        float inv = bn2g[oc] * rsqrtf(bn2v[oc] + 1e-5f);
        b2f[oc] = bn2b[oc] - bn2m[oc] * inv;
    }

    __shared__ float sZ[16][8], sH1[16][64], sH2[16][64], sG[16][2], sF[16][10];
    if (j < 8) sZ[b][j] = z[b * 8 + j];
    __syncthreads();
    float a = b1[j];
    #pragma unroll
    for (int k = 0; k < 8; ++k) a += sZ[b][k] * w1[j * 8 + k];
    sH1[b][j] = fmaxf(a, 0.f);
    __syncthreads();
    float a2 = b2[j];
    for (int k = 0; k < 64; ++k) a2 += sH1[b][k] * w2[j * 64 + k];
    sH2[b][j] = fmaxf(a2, 0.f);
    __syncthreads();
    if (j < 2) {
        float g = hgb[j];
        for (int k = 0; k < 64; ++k) g += sH2[b][k] * hgw[j * 64 + k];
        sG[b][j] = 1.f / (1.f + __expf(-g));
    }
    if (j < 10) {
        float f = hfb[j];
        for (int k = 0; k < 64; ++k) f += sH2[b][k] * hfw[j * 64 + k];
        sF[b][j] = f;
    }
    __syncthreads();
    if (j < 5) {
        float gs = sG[b][0] + sG[b][1] + 1e-12f;
        float alpha = (j < 2 ? sG[b][0] : sG[b][1]) / gs;
        float gamma = 1.f + 0.1f * sF[b][j];
        float beta  = 0.1f * sF[b][5 + j];
        float r = rs[0];
        coefA[b * 5 + j] = r * alpha * gamma;
        coefB[b * 5 + j] = r * alpha * beta;
    }
}

// ---------------------------------------------------------------------------
// k_main: fused conv1+bn1+silu+conv2+bn2 + FiLM + residual (f32 out).
// grid (16,16,16), 320 threads, 32x32 tile per block.
// v9: single-pass conv1 over all 16 oc (acc[16][4]) into full sT1[16] ->
// barriers 4->2, conv1 LDS reads/unpack halved. Tap loops are ic-outer
// (unroll 1) with dy fully unrolled over 3 explicit row pointers (no div/mod).
// Weights/biases via wave-uniform global reads (SGPR/K$ path).
// ---------------------------------------------------------------------------
__global__ __launch_bounds__(320, 2) void k_main(
    const float* __restrict__ ev, const float* __restrict__ fr,
    const float* __restrict__ w1f, const float* __restrict__ b1f,
    const float* __restrict__ w2f, const float* __restrict__ b2f,
    const float* __restrict__ coefA, const float* __restrict__ coefB,
    float* __restrict__ out)
{
    __shared__ u32 sIn[5][36][20];      // bf16-pair input tile, 14.4 KB
    __shared__ u32 sT1[16][34][20];     // bf16-pair conv1 output (all 16 oc), 43.52 KB

    int tid = threadIdx.x;
    int b = blockIdx.z;
    int ty0 = blockIdx.y * 32, tx0 = blockIdx.x * 32;

    // stage input tile as bf16 pairs (3600 u32)
    for (int idx = tid; idx < 3600; idx += 320) {
        int chn = idx / 720, rem = idx % 720;
        int r = rem / 20, cc = rem % 20;
        int gy = ty0 - 2 + r, gx = tx0 - 2 + 2 * cc;
        float v0 = 0.f, v1 = 0.f;
        if (gy >= 0 && gy < W512 && 2 * cc < 36) {
            const float* src = (chn < 2) ? (ev + (size_t)(b * 2 + chn) * HW)
                                         : (fr + (size_t)(b * 3 + chn - 2) * HW);
            size_t o = (size_t)gy * W512;
            if (gx >= 0 && gx < W512)         v0 = src[o + gx];
            if (gx + 1 >= 0 && gx + 1 < W512) v1 = src[o + gx + 1];
        }
        sIn[chn][r][cc] = f2b_rtne(v0) | (f2b_rtne(v1) << 16);
    }
    __syncthreads();

    int pr = tid >> 3, pc0 = (tid & 7) << 2, pcu = (tid & 7) << 1;

    // ---- conv1 (+bn1+silu): all 16 oc in one pass (306 strips <= 320) ----
    if (tid < 306) {
        int r = tid / 9, cu = (tid % 9) * 2;
        float acc[16][4];
        #pragma unroll
        for (int oc = 0; oc < 16; ++oc) {
            float bb = b1f[oc];            // uniform -> SGPR
            #pragma unroll
            for (int p = 0; p < 4; ++p) acc[oc][p] = bb;
        }
        #pragma unroll 1
        for (int ic = 0; ic < 5; ++ic) {
            const u32* r0p = &sIn[ic][r][cu];
            const u32* r1p = &sIn[ic][r + 1][cu];
            const u32* r2p = &sIn[ic][r + 2][cu];
            #pragma unroll
            for (int dy = 0; dy < 3; ++dy) {
                const u32* rp = (dy == 0) ? r0p : (dy == 1) ? r1p : r2p;
                u32 q0 = rp[0], q1 = rp[1], q2 = rp[2];
                float x[6];
                x[0] = lo16(q0); x[1] = hi16(q0);
                x[2] = lo16(q1); x[3] = hi16(q1);
                x[4] = lo16(q2); x[5] = hi16(q2);
                #pragma unroll
                for (int dx = 0; dx < 3; ++dx) {
                    const float* wv = &w1f[((ic * 3 + dy) * 3 + dx) * 16];  // uniform
                    #pragma unroll
                    for (int oc = 0; oc < 16; ++oc) {
                        float w = wv[oc];
                        #pragma unroll
                        for (int p = 0; p < 4; ++p) acc[oc][p] += x[dx + p] * w;
                    }
                }
            }
        }
        int gy1 = ty0 - 1 + r;
        bool rowok = (gy1 >= 0 && gy1 < W512);
        int c0 = cu * 2;
        #pragma unroll
        for (int oc = 0; oc < 16; ++oc) {
            float sl[4];
            #pragma unroll
            for (int p = 0; p < 4; ++p) {
                float vv = acc[oc][p];
                float s2 = vv / (1.f + __expf(-vv));
                int gx1 = tx0 - 1 + c0 + p;
                // conv2's SAME padding sees ZEROS outside image
                if (!rowok || gx1 < 0 || gx1 >= W512) s2 = 0.f;
                sl[p] = s2;
            }
            sT1[oc][r][cu]     = f2b_rtne(sl[0]) | (f2b_rtne(sl[1]) << 16);
            sT1[oc][r][cu + 1] = f2b_rtne(sl[2]) | (f2b_rtne(sl[3]) << 16);
        }
    }
    __syncthreads();

    // ---- conv2 over all 16 input channels + epilogue ----
    if (tid < 256) {
        float acc2[5][4];
        #pragma unroll
        for (int oc = 0; oc < 5; ++oc) {
            float bb = b2f[oc];            // uniform -> SGPR
            #pragma unroll
            for (int p = 0; p < 4; ++p) acc2[oc][p] = bb;
        }
        #pragma unroll 1
        for (int ic = 0; ic < 16; ++ic) {
            const u32* r0p = &sT1[ic][pr][pcu];
            const u32* r1p = &sT1[ic][pr + 1][pcu];
            const u32* r2p = &sT1[ic][pr + 2][pcu];
            #pragma unroll
            for (int dy = 0; dy < 3; ++dy) {
                const u32* rp = (dy == 0) ? r0p : (dy == 1) ? r1p : r2p;
                u32 q0 = rp[0], q1 = rp[1], q2 = rp[2];
                float x[6];
                x[0] = lo16(q0); x[1] = hi16(q0);
                x[2] = lo16(q1); x[3] = hi16(q1);
                x[4] = lo16(q2); x[5] = hi16(q2);
                #pragma unroll
                for (int dx = 0; dx < 3; ++dx) {
                    const float* wv = &w2f[((ic * 3 + dy) * 3 + dx) * 8];   // uniform
                    #pragma unroll
                    for (int oc = 0; oc < 5; ++oc) {
                        float w = wv[oc];
                        #pragma unroll
                        for (int p = 0; p < 4; ++p) acc2[oc][p] += x[dx + p] * w;
                    }
                }
            }
        }

        float cA[5], cB[5];
        #pragma unroll
        for (int oc = 0; oc < 5; ++oc) {
            cA[oc] = coefA[b * 5 + oc];    // uniform -> SGPR
            cB[oc] = coefB[b * 5 + oc];
        }
        int gy = ty0 + pr, gx0 = tx0 + pc0;
        #pragma unroll
        for (int oc = 0; oc < 5; ++oc) {
            size_t ioff;
            const float* src;
            if (oc < 2) { src = ev; ioff = (size_t)(b * 2 + oc) * HW; }
            else        { src = fr; ioff = (size_t)(b * 3 + oc - 2) * HW; }
            float4 iv = *reinterpret_cast<const float4*>(&src[ioff + (size_t)gy * W512 + gx0]);
            float4 pk;
            pk.x = iv.x + cA[oc] * acc2[oc][0] + cB[oc];
            pk.y = iv.y + cA[oc] * acc2[oc][1] + cB[oc];
            pk.z = iv.z + cA[oc] * acc2[oc][2] + cB[oc];
            pk.w = iv.w + cA[oc] * acc2[oc][3] + cB[oc];
            size_t off;
            if (oc < 2) off = (size_t)(b * 2 + oc) * HW + (size_t)gy * W512 + gx0;
            else        off = (size_t)2 * 16 * HW + (size_t)(b * 3 + oc - 2) * HW + (size_t)gy * W512 + gx0;
            *reinterpret_cast<float4*>(out + off) = pk;
        }
    }
}

// ---------------------------------------------------------------------------
extern "C" void kernel_launch(void* const* d_in, const int* in_sizes, int n_in,
                              void* d_out, int out_size, void* d_ws, size_t ws_size,
                              hipStream_t stream)
{
    const float* ev = (const float*)d_in[0];
    const float* fr = (const float*)d_in[1];

    float* ws = (float*)d_ws;
    float* coefA    = ws;            // 80
    float* coefB    = ws + 80;       // 80
    float* zbuf     = ws + 256;      // 128
    float* w1f      = ws + 512;      // 720  [tap45][oc16]
    float* b1f      = ws + 1232;     // 16
    float* w2f      = ws + 1248;     // 1152 [tap144][oc8]
    float* b2f      = ws + 2400;     // 5
    float* partials = ws + 2560;     // 16384 (fast path) -> total 75776 B

    bool fast = (ws_size >= 75776);
    int nb   = fast ? 32 : 1;
    int nblk = fast ? 512 : 16;
    k_band<<<dim3(nblk), dim3(1024), 0, stream>>>(ev, fr, nb, partials, zbuf);
    if (fast) k_finalize<<<dim3(16), dim3(256), 0, stream>>>(partials, zbuf);

    k_mlp<<<dim3(1), dim3(64, 16), 0, stream>>>(zbuf,
        (const float*)d_in[12], (const float*)d_in[13], (const float*)d_in[14], (const float*)d_in[15],
        (const float*)d_in[16], (const float*)d_in[17], (const float*)d_in[18], (const float*)d_in[19],
        (const float*)d_in[20],
        (const float*)d_in[2], (const float*)d_in[3], (const float*)d_in[4], (const float*)d_in[5],
        (const float*)d_in[6], (const float*)d_in[7], (const float*)d_in[8], (const float*)d_in[9],
        (const float*)d_in[10], (const float*)d_in[11],
        coefA, coefB, w1f, b1f, w2f, b2f);

    k_main<<<dim3(16, 16, 16), dim3(320), 0, stream>>>(ev, fr,
        w1f, b1f, w2f, b2f, coefA, coefB, (float*)d_out);
}

// Round 10
// 226.441 us; speedup vs baseline: 1.6424x; 1.6424x over previous
//
#include <hip/hip_runtime.h>

typedef unsigned int   u32;
typedef unsigned short u16;

#define HW 262144   // 512*512
#define W512 512

typedef __attribute__((ext_vector_type(8))) short short8;   // 8 bf16 (4 VGPRs)
typedef __attribute__((ext_vector_type(4))) float f32x4;

__device__ __forceinline__ u32 f2b_rtne(float f) {   // f32 -> bf16 bits (RTNE)
    union { float f; u32 i; } c; c.f = f;
    u32 u = c.i;
    return (u + 0x7FFFu + ((u >> 16) & 1u)) >> 16;
}

// ---------------------------------------------------------------------------
// k_band: metrics over a horizontal band. nb bands/batch (32 fast, 1 slow).
// ---------------------------------------------------------------------------
__global__ __launch_bounds__(1024) void k_band(
    const float* __restrict__ ev, const float* __restrict__ fr,
    int nb, float* __restrict__ partials, float* __restrict__ z)
{
    __shared__ float sY[18][512];
    __shared__ float sE[18][512];
    __shared__ float cellPart[1024];
    __shared__ float cellFull[256];
    __shared__ float red[16][8];

    int blk = blockIdx.x;
    int b = blk / nb, band = blk % nb;
    int rowsPerBand = 512 / nb;
    int chunks = rowsPerBand >> 4;
    int rBase = band * rowsPerBand;
    int tid = threadIdx.x;

    const float* Pp = ev + (size_t)(b * 2)     * HW;
    const float* Np = ev + (size_t)(b * 2 + 1) * HW;
    const float* Rp = fr + (size_t)(b * 3)     * HW;
    const float* Gp = fr + (size_t)(b * 3 + 1) * HW;
    const float* Bp = fr + (size_t)(b * 3 + 2) * HW;

    if (nb == 1 && tid < 256) cellFull[tid] = 0.f;

    float aY = 0, aY2 = 0, aL = 0, aL2 = 0, aG = 0, aPb = 0, aLE = 0, aLE2 = 0;

    for (int ch = 0; ch < chunks; ++ch) {
        int r0 = rBase + ch * 16;
        for (int idx = tid; idx < 18 * 512; idx += 1024) {
            int rl = idx >> 9, c = idx & 511;
            int gy = r0 - 1 + rl;
            float y = 0.f, e = 0.f;
            if (gy >= 0 && gy < W512) {
                size_t o = (size_t)gy * W512 + c;
                float rr = Rp[o], gg = Gp[o], bb = Bp[o];
                y = fminf(fmaxf(0.299f * rr + 0.587f * gg + 0.114f * bb, 0.f), 1.f);
                e = fmaxf((Pp[o] + Np[o]) * (1.f / 255.f), 0.f);
            }
            sY[rl][c] = y; sE[rl][c] = e;
        }
        __syncthreads();

        float ce = 0.f;
        int hf = tid >> 9, col = tid & 511;
        for (int i = 0; i < 8; ++i) {
            int rl = hf + 2 * i;
            int lr = rl + 1;
            int gy = r0 + rl;
            float y   = sY[lr][col];
            float yu  = sY[lr - 1][col], yd = sY[lr + 1][col];
            float yl  = col        ? sY[lr][col - 1]     : 0.f;
            float yr  = col < 511  ? sY[lr][col + 1]     : 0.f;
            float yul = col        ? sY[lr - 1][col - 1] : 0.f;
            float yur = col < 511  ? sY[lr - 1][col + 1] : 0.f;
            float ydl = col        ? sY[lr + 1][col - 1] : 0.f;
            float ydr = col < 511  ? sY[lr + 1][col + 1] : 0.f;
            float lap = yu + yd + yl + yr - 4.f * y;
            float gx  = (yur + 2.f * yr + ydr) - (yul + 2.f * yl + ydl);
            float gy2 = (ydl + 2.f * yd + ydr) - (yul + 2.f * yu + yur);
            float gm  = sqrtf(gx * gx + gy2 * gy2);
            float e   = sE[lr][col];
            float el  = col       ? sE[lr][col - 1] : 0.f;
            float er  = col < 511 ? sE[lr][col + 1] : 0.f;
            float lapE = sE[lr - 1][col] + sE[lr + 1][col] + el + er - 4.f * e;
            size_t o = (size_t)gy * W512 + col;
            float pn = Pp[o] * (1.f / 255.f);
            float nn = Np[o] * (1.f / 255.f);
            float pb = (pn - nn) / (pn + nn + 1e-12f);
            aY += y; aY2 += y * y; aL += lap; aL2 += lap * lap; aG += gm;
            aPb += pb; aLE += lapE; aLE2 += lapE * lapE; ce += e;
        }
        cellPart[tid] = ce;
        __syncthreads();
        if (tid < 16) {
            float s = 0.f;
            int c0 = tid * 32;
            for (int h2 = 0; h2 < 2; ++h2)
                for (int c = 0; c < 32; ++c) s += cellPart[h2 * 512 + c0 + c];
            if (nb == 1) cellFull[(r0 >> 5) * 16 + tid] += s;
            else         partials[(size_t)blk * 32 + 9 + tid] = s;
        }
        __syncthreads();
    }

    float v[8] = {aY, aY2, aL, aL2, aG, aPb, aLE, aLE2};
    #pragma unroll
    for (int off = 32; off; off >>= 1)
        #pragma unroll
        for (int k = 0; k < 8; ++k) v[k] += __shfl_down(v[k], off);
    int lane = tid & 63, wid = tid >> 6;
    if (lane == 0)
        for (int k = 0; k < 8; ++k) red[wid][k] = v[k];
    __syncthreads();

    if (tid == 0) {
        float s[8];
        for (int k = 0; k < 8; ++k) {
            float t = 0.f;
            for (int w = 0; w < 16; ++w) t += red[w][k];
            s[k] = t;
        }
        if (nb > 1) {
            float* rec = partials + (size_t)blk * 32;
            for (int k = 0; k < 8; ++k) rec[k] = s[k];
        } else {
            float c1 = 0.f, c2 = 0.f, ct = 0.f;
            for (int j = 0; j < 256; ++j) {
                float m = cellFull[j] * (1.f / 1024.f);
                c1 += m; c2 += m * m; ct += cellFull[j];
            }
            const float FN = 262144.f;
            float muY   = s[0] / FN;
            float stdY  = sqrtf(fmaxf(s[1] / FN - muY * muY, 0.f));
            float varlp = fmaxf(s[3] - s[2] * s[2] / FN, 0.f) / (FN - 1.f);
            float gmean = s[4] / FN;
            float mc = c1 * (1.f / 256.f);
            float vc = fmaxf(c2 * (1.f / 256.f) - mc * mc, 0.f);
            float cv = sqrtf(vc) / (mc + 1e-12f);
            float dens = ct / FN;
            float pb = s[5] / FN;
            float varlpE = fmaxf(s[7] - s[6] * s[6] / FN, 0.f) / (FN - 1.f);
            float* zb = z + b * 8;
            zb[0] = muY; zb[1] = stdY; zb[2] = varlp; zb[3] = gmean;
            zb[4] = cv;  zb[5] = dens; zb[6] = pb;    zb[7] = varlpE;
        }
    }
}

// ---------------------------------------------------------------------------
// k_finalize (fast path): merge 32 band records per batch -> z[16][8]
// ---------------------------------------------------------------------------
__global__ __launch_bounds__(256) void k_finalize(
    const float* __restrict__ partials, float* __restrict__ z)
{
    __shared__ float sred[8];
    __shared__ float rr[4][3];
    int b = blockIdx.x, tid = threadIdx.x;
    if (tid < 8) {
        float s = 0.f;
        for (int band = 0; band < 32; ++band)
            s += partials[(size_t)(b * 32 + band) * 32 + tid];
        sred[tid] = s;
    }
    int cr = tid >> 4, cc = tid & 15;
    float cell = partials[(size_t)(b * 32 + 2 * cr)     * 32 + 9 + cc]
               + partials[(size_t)(b * 32 + 2 * cr + 1) * 32 + 9 + cc];
    float m = cell * (1.f / 1024.f);
    float c1 = m, c2 = m * m, ct = cell;
    #pragma unroll
    for (int off = 32; off; off >>= 1) {
        c1 += __shfl_down(c1, off);
        c2 += __shfl_down(c2, off);
        ct += __shfl_down(ct, off);
    }
    int lane = tid & 63, wid = tid >> 6;
    if (lane == 0) { rr[wid][0] = c1; rr[wid][1] = c2; rr[wid][2] = ct; }
    __syncthreads();
    if (tid == 0) {
        float C1 = rr[0][0] + rr[1][0] + rr[2][0] + rr[3][0];
        float C2 = rr[0][1] + rr[1][1] + rr[2][1] + rr[3][1];
        float CT = rr[0][2] + rr[1][2] + rr[2][2] + rr[3][2];
        const float FN = 262144.f;
        float muY   = sred[0] / FN;
        float stdY  = sqrtf(fmaxf(sred[1] / FN - muY * muY, 0.f));
        float varlp = fmaxf(sred[3] - sred[2] * sred[2] / FN, 0.f) / (FN - 1.f);
        float gmean = sred[4] / FN;
        float mc = C1 * (1.f / 256.f);
        float vc = fmaxf(C2 * (1.f / 256.f) - mc * mc, 0.f);
        float cv = sqrtf(vc) / (mc + 1e-12f);
        float dens = CT / FN;
        float pb = sred[5] / FN;
        float varlpE = fmaxf(sred[7] - sred[6] * sred[6] / FN, 0.f) / (FN - 1.f);
        float* zb = z + b * 8;
        zb[0] = muY; zb[1] = stdY; zb[2] = varlp; zb[3] = gmean;
        zb[4] = cv;  zb[5] = dens; zb[6] = pb;    zb[7] = varlpE;
    }
}

// ---------------------------------------------------------------------------
// k_mlp: metrics MLP -> coefs  +  build bf16 MFMA weight fragments in ws.
// K-conventions (shared by A-pack here and B-gather in k_main):
//  conv1: K=32/mfma, k = g*8+j -> tap = m*4+g (>=9 pad0), ic = j (>=5 pad0)
//  conv2: K=32/mfma, k = g*8+j -> tap = 2m+(g>>1) (>=9 pad0), ic=(g&1)*8+j
// A lane&15 = oc row. Biases: b1f separate; conv2 bias folded into cBp.
// ---------------------------------------------------------------------------
__global__ __launch_bounds__(1024) void k_mlp(
    const float* __restrict__ z,
    const float* __restrict__ w1, const float* __restrict__ b1,
    const float* __restrict__ w2, const float* __restrict__ b2,
    const float* __restrict__ hgw, const float* __restrict__ hgb,
    const float* __restrict__ hfw, const float* __restrict__ hfb,
    const float* __restrict__ rs,
    const float* __restrict__ c1w,
    const float* __restrict__ bn1g, const float* __restrict__ bn1b,
    const float* __restrict__ bn1m, const float* __restrict__ bn1v,
    const float* __restrict__ c2w,
    const float* __restrict__ bn2g, const float* __restrict__ bn2b,
    const float* __restrict__ bn2m, const float* __restrict__ bn2v,
    float* __restrict__ coefA, float* __restrict__ cBp,
    u16* __restrict__ w1frag, u16* __restrict__ w2frag,
    float* __restrict__ b1f)
{
    int j = threadIdx.x, b = threadIdx.y;
    int ft = b * 64 + j;   // flat 0..1023

    for (int t = ft; t < 1536; t += 1024) {          // w1frag[m][lane][8]
        int m = t >> 9, ln = (t >> 3) & 63, sl = t & 7;
        int oc = ln & 15, gg = ln >> 4;
        int tap = m * 4 + gg;
        float v = 0.f;
        if (tap < 9 && sl < 5)
            v = c1w[oc * 45 + sl * 9 + tap] * (bn1g[oc] * rsqrtf(bn1v[oc] + 1e-5f));
        w1frag[t] = (u16)f2b_rtne(v);
    }
    for (int t = ft; t < 2560; t += 1024) {          // w2frag[m][lane][8]
        int m = t >> 9, ln = (t >> 3) & 63, sl = t & 7;
        int oc = ln & 15, gg = ln >> 4;
        int tap = 2 * m + (gg >> 1);
        int ic = (gg & 1) * 8 + sl;
        float v = 0.f;
        if (oc < 5 && tap < 9)
            v = c2w[oc * 144 + ic * 9 + tap] * (bn2g[oc] * rsqrtf(bn2v[oc] + 1e-5f));
        w2frag[t] = (u16)f2b_rtne(v);
    }
    if (ft < 16) {
        float inv = bn1g[ft] * rsqrtf(bn1v[ft] + 1e-5f);
        b1f[ft] = bn1b[ft] - bn1m[ft] * inv;
    }

    __shared__ float sZ[16][8], sH1[16][64], sH2[16][64], sG[16][2], sF[16][10];
    if (j < 8) sZ[b][j] = z[b * 8 + j];
    __syncthreads();
    float a = b1[j];
    #pragma unroll
    for (int k = 0; k < 8; ++k) a += sZ[b][k] * w1[j * 8 + k];
    sH1[b][j] = fmaxf(a, 0.f);
    __syncthreads();
    float a2 = b2[j];
    for (int k = 0; k < 64; ++k) a2 += sH1[b][k] * w2[j * 64 + k];
    sH2[b][j] = fmaxf(a2, 0.f);
    __syncthreads();
    if (j < 2) {
        float g = hgb[j];
        for (int k = 0; k < 64; ++k) g += sH2[b][k] * hgw[j * 64 + k];
        sG[b][j] = 1.f / (1.f + __expf(-g));
    }
    if (j < 10) {
        float f = hfb[j];
        for (int k = 0; k < 64; ++k) f += sH2[b][k] * hfw[j * 64 + k];
        sF[b][j] = f;
    }
    __syncthreads();
    if (j < 5) {
        float gs = sG[b][0] + sG[b][1] + 1e-12f;
        float alpha = (j < 2 ? sG[b][0] : sG[b][1]) / gs;
        float gamma = 1.f + 0.1f * sF[b][j];
        float beta  = 0.1f * sF[b][5 + j];
        float r = rs[0];
        float inv2 = bn2g[j] * rsqrtf(bn2v[j] + 1e-5f);
        float b2fold = bn2b[j] - bn2m[j] * inv2;
        float cA = r * alpha * gamma;
        coefA[b * 5 + j] = cA;
        cBp[b * 5 + j]   = r * alpha * beta + cA * b2fold;  // conv2 bias folded
    }
}

// ---------------------------------------------------------------------------
// k_main (MFMA): conv1+bn1+silu+conv2+bn2 + FiLM + residual.
// grid (16,16,16), 256 threads (4 waves), 32x32 tile.
// Channel-minor LDS: sIn 16B/px (8 ic bf16), sT1 48B/px (16 ic + pad) ->
// each B-fragment is ONE aligned ds_read_b128, bank-conflict-free.
// ---------------------------------------------------------------------------
__global__ __launch_bounds__(256, 2) void k_main(
    const float* __restrict__ ev, const float* __restrict__ fr,
    const u16* __restrict__ w1frag, const u16* __restrict__ w2frag,
    const float* __restrict__ b1f,
    const float* __restrict__ coefA, const float* __restrict__ cBp,
    float* __restrict__ out)
{
    __shared__ __align__(16) u16 sIn[36 * 36 * 8];    // 20736 B
    __shared__ __align__(16) u16 sT1[34 * 34 * 24];   // 55488 B

    int tid = threadIdx.x;
    int lane = tid & 63, wv = tid >> 6;
    int g = lane >> 4, col = lane & 15;
    int b = blockIdx.z;
    int ty0 = blockIdx.y * 32, tx0 = blockIdx.x * 32;

    const float* p0 = ev + (size_t)(b * 2)     * HW;
    const float* p1 = ev + (size_t)(b * 2 + 1) * HW;
    const float* p2 = fr + (size_t)(b * 3)     * HW;
    const float* p3 = fr + (size_t)(b * 3 + 1) * HW;
    const float* p4 = fr + (size_t)(b * 3 + 2) * HW;

    // ---- stage sIn: channel-minor bf16, zeros outside image ----
    for (int idx = tid; idx < 1296; idx += 256) {
        int r = idx / 36, c = idx % 36;
        int gy = ty0 - 2 + r, gx = tx0 - 2 + c;
        u32 q0 = 0, q1 = 0, q2 = 0;
        if (gy >= 0 && gy < W512 && gx >= 0 && gx < W512) {
            size_t o = (size_t)gy * W512 + gx;
            q0 = f2b_rtne(p0[o]) | (f2b_rtne(p1[o]) << 16);
            q1 = f2b_rtne(p2[o]) | (f2b_rtne(p3[o]) << 16);
            q2 = f2b_rtne(p4[o]);
        }
        uint4 pk; pk.x = q0; pk.y = q1; pk.z = q2; pk.w = 0;
        *reinterpret_cast<uint4*>(&sIn[idx * 8]) = pk;
    }

    // ---- A fragments + per-lane B byte-offsets ----
    short8 a1[3], a2f[5];
    #pragma unroll
    for (int m = 0; m < 3; ++m)
        a1[m] = *reinterpret_cast<const short8*>(&w1frag[(m * 64 + lane) * 8]);
    #pragma unroll
    for (int m = 0; m < 5; ++m)
        a2f[m] = *reinterpret_cast<const short8*>(&w2frag[(m * 64 + lane) * 8]);
    f32x4 b1v = *reinterpret_cast<const f32x4*>(&b1f[g * 4]);

    int boff1[3];
    #pragma unroll
    for (int m = 0; m < 3; ++m) {
        int tap = m * 4 + g; if (tap > 8) tap = 8;
        boff1[m] = ((tap / 3) * 36 + (tap % 3)) * 16;
    }
    int boff2[5];
    #pragma unroll
    for (int m = 0; m < 5; ++m) {
        int tap = 2 * m + (g >> 1); if (tap > 8) tap = 8;
        boff2[m] = ((tap / 3) * 34 + (tap % 3)) * 48 + (g & 1) * 16;
    }

    __syncthreads();

    // ---- conv1: 73 N-tiles over 34x34 domain ----
    for (int t = wv; t < 73; t += 4) {
        int q = t * 16 + col;
        int qc = q > 1155 ? 1155 : q;
        int r = qc / 34, c = qc - r * 34;
        const char* base = (const char*)&sIn[(r * 36 + c) * 8];
        f32x4 acc = {0.f, 0.f, 0.f, 0.f};
        #pragma unroll
        for (int m = 0; m < 3; ++m) {
            short8 bf = *reinterpret_cast<const short8*>(base + boff1[m]);
            acc = __builtin_amdgcn_mfma_f32_16x16x32_bf16(a1[m], bf, acc, 0, 0, 0);
        }
        // bias + silu; zero outside image (conv2 SAME-pads with zeros)
        int gy1 = ty0 - 1 + r, gx1 = tx0 - 1 + c;
        bool inimg = (gy1 >= 0 && gy1 < W512 && gx1 >= 0 && gx1 < W512);
        float v0 = acc[0] + b1v[0], v1 = acc[1] + b1v[1];
        float v2 = acc[2] + b1v[2], v3 = acc[3] + b1v[3];
        v0 = v0 / (1.f + __expf(-v0)); v1 = v1 / (1.f + __expf(-v1));
        v2 = v2 / (1.f + __expf(-v2)); v3 = v3 / (1.f + __expf(-v3));
        if (!inimg) { v0 = v1 = v2 = v3 = 0.f; }
        if (q <= 1155) {
            uint2 pk;
            pk.x = f2b_rtne(v0) | (f2b_rtne(v1) << 16);
            pk.y = f2b_rtne(v2) | (f2b_rtne(v3) << 16);
            *reinterpret_cast<uint2*>(&sT1[(r * 34 + c) * 24 + g * 4]) = pk;
        }
    }
    __syncthreads();

    // ---- conv2 + epilogue: 64 N-tiles over 32x32 ----
    float cA0 = coefA[b * 5 + 0], cA1 = coefA[b * 5 + 1], cA2 = coefA[b * 5 + 2];
    float cA3 = coefA[b * 5 + 3], cA4 = coefA[b * 5 + 4];
    float cB0 = cBp[b * 5 + 0], cB1 = cBp[b * 5 + 1], cB2 = cBp[b * 5 + 2];
    float cB3 = cBp[b * 5 + 3], cB4 = cBp[b * 5 + 4];
    const size_t OUT2 = (size_t)32 * HW;

    for (int t = wv; t < 64; t += 4) {
        int q = t * 16 + col;
        int r = q >> 5, c = q & 31;
        const char* base = (const char*)&sT1[(r * 34 + c) * 24];
        f32x4 acc = {0.f, 0.f, 0.f, 0.f};
        #pragma unroll
        for (int m = 0; m < 5; ++m) {
            short8 bf = *reinterpret_cast<const short8*>(base + boff2[m]);
            acc = __builtin_amdgcn_mfma_f32_16x16x32_bf16(a2f[m], bf, acc, 0, 0, 0);
        }
        size_t px = (size_t)(ty0 + r) * W512 + (tx0 + c);
        if (g == 0) {   // oc 0..3
            out[(size_t)(b * 2 + 0) * HW + px] = p0[px] + cA0 * acc[0] + cB0;
            out[(size_t)(b * 2 + 1) * HW + px] = p1[px] + cA1 * acc[1] + cB1;
            out[OUT2 + (size_t)(b * 3 + 0) * HW + px] = p2[px] + cA2 * acc[2] + cB2;
            out[OUT2 + (size_t)(b * 3 + 1) * HW + px] = p3[px] + cA3 * acc[3] + cB3;
        } else if (g == 1) {   // oc 4
            out[OUT2 + (size_t)(b * 3 + 2) * HW + px] = p4[px] + cA4 * acc[0] + cB4;
        }
    }
}

// ---------------------------------------------------------------------------
extern "C" void kernel_launch(void* const* d_in, const int* in_sizes, int n_in,
                              void* d_out, int out_size, void* d_ws, size_t ws_size,
                              hipStream_t stream)
{
    const float* ev = (const float*)d_in[0];
    const float* fr = (const float*)d_in[1];

    char* wb = (char*)d_ws;
    float* coefA    = (float*)(wb + 0);      // 80 f
    float* cBp      = (float*)(wb + 320);    // 80 f
    float* b1f      = (float*)(wb + 640);    // 16 f
    u16*   w1frag   = (u16*) (wb + 768);     // 1536 u16
    u16*   w2frag   = (u16*) (wb + 3840);    // 2560 u16
    float* zbuf     = (float*)(wb + 8960);   // 128 f
    float* partials = (float*)(wb + 10240);  // 16384 f  -> total 75776 B

    bool fast = (ws_size >= 75776);
    int nb   = fast ? 32 : 1;
    int nblk = fast ? 512 : 16;
    k_band<<<dim3(nblk), dim3(1024), 0, stream>>>(ev, fr, nb, partials, zbuf);
    if (fast) k_finalize<<<dim3(16), dim3(256), 0, stream>>>(partials, zbuf);

    k_mlp<<<dim3(1), dim3(64, 16), 0, stream>>>(zbuf,
        (const float*)d_in[12], (const float*)d_in[13], (const float*)d_in[14], (const float*)d_in[15],
        (const float*)d_in[16], (const float*)d_in[17], (const float*)d_in[18], (const float*)d_in[19],
        (const float*)d_in[20],
        (const float*)d_in[2], (const float*)d_in[3], (const float*)d_in[4], (const float*)d_in[5],
        (const float*)d_in[6], (const float*)d_in[7], (const float*)d_in[8], (const float*)d_in[9],
        (const float*)d_in[10], (const float*)d_in[11],
        coefA, cBp, w1frag, w2frag, b1f);

    k_main<<<dim3(16, 16, 16), dim3(256), 0, stream>>>(ev, fr,
        w1frag, w2frag, b1f, coefA, cBp, (float*)d_out);
}

// Round 11
// 205.694 us; speedup vs baseline: 1.8080x; 1.1009x over previous
//
#include <hip/hip_runtime.h>
#include <hip/hip_bf16.h>

typedef unsigned int   u32;
typedef unsigned short u16;

#define HW 262144   // 512*512
#define W512 512

typedef __attribute__((ext_vector_type(8))) short short8;   // 8 bf16 (4 VGPRs)
typedef __attribute__((ext_vector_type(4))) float f32x4;

__device__ __forceinline__ u32 f2b_rtne(float f) {   // f32 -> bf16 bits (RTNE)
    union { float f; u32 i; } c; c.f = f;
    u32 u = c.i;
    return (u + 0x7FFFu + ((u >> 16) & 1u)) >> 16;
}
__device__ __forceinline__ u32 pk_bf16(float lo, float hi) {  // 2xf32 -> packed bf16 pair
    float2 t; t.x = lo; t.y = hi;
    __hip_bfloat162 h = __float22bfloat162_rn(t);
    return *reinterpret_cast<u32*>(&h);
}
__device__ __forceinline__ float silu_fast(float v) {
    return v * __builtin_amdgcn_rcpf(1.f + __expf(-v));
}

// ---------------------------------------------------------------------------
// k_band: metrics over a horizontal band. nb bands/batch (32 fast, 1 slow).
// Vectorized float4 staging (rows are 16B-aligned, 512 % 4 == 0).
// ---------------------------------------------------------------------------
__global__ __launch_bounds__(1024) void k_band(
    const float* __restrict__ ev, const float* __restrict__ fr,
    int nb, float* __restrict__ partials, float* __restrict__ z)
{
    __shared__ float sY[18][512];
    __shared__ float sE[18][512];
    __shared__ float cellPart[1024];
    __shared__ float cellFull[256];
    __shared__ float red[16][8];

    int blk = blockIdx.x;
    int b = blk / nb, band = blk % nb;
    int rowsPerBand = 512 / nb;
    int chunks = rowsPerBand >> 4;
    int rBase = band * rowsPerBand;
    int tid = threadIdx.x;

    const float* Pp = ev + (size_t)(b * 2)     * HW;
    const float* Np = ev + (size_t)(b * 2 + 1) * HW;
    const float* Rp = fr + (size_t)(b * 3)     * HW;
    const float* Gp = fr + (size_t)(b * 3 + 1) * HW;
    const float* Bp = fr + (size_t)(b * 3 + 2) * HW;

    if (nb == 1 && tid < 256) cellFull[tid] = 0.f;

    float aY = 0, aY2 = 0, aL = 0, aL2 = 0, aG = 0, aPb = 0, aLE = 0, aLE2 = 0;

    for (int ch = 0; ch < chunks; ++ch) {
        int r0 = rBase + ch * 16;
        // stage 18 rows x 512 cols as float4 groups (2304 groups)
        for (int idx = tid; idx < 2304; idx += 1024) {
            int rl = idx >> 7, k4 = (idx & 127) << 2;
            int gy = r0 - 1 + rl;
            float4 y4 = {0.f, 0.f, 0.f, 0.f};
            float4 e4 = {0.f, 0.f, 0.f, 0.f};
            if (gy >= 0 && gy < W512) {
                size_t o = (size_t)gy * W512 + k4;
                float4 R = *reinterpret_cast<const float4*>(Rp + o);
                float4 G = *reinterpret_cast<const float4*>(Gp + o);
                float4 B = *reinterpret_cast<const float4*>(Bp + o);
                float4 P = *reinterpret_cast<const float4*>(Pp + o);
                float4 N = *reinterpret_cast<const float4*>(Np + o);
                y4.x = fminf(fmaxf(0.299f * R.x + 0.587f * G.x + 0.114f * B.x, 0.f), 1.f);
                y4.y = fminf(fmaxf(0.299f * R.y + 0.587f * G.y + 0.114f * B.y, 0.f), 1.f);
                y4.z = fminf(fmaxf(0.299f * R.z + 0.587f * G.z + 0.114f * B.z, 0.f), 1.f);
                y4.w = fminf(fmaxf(0.299f * R.w + 0.587f * G.w + 0.114f * B.w, 0.f), 1.f);
                e4.x = fmaxf((P.x + N.x) * (1.f / 255.f), 0.f);
                e4.y = fmaxf((P.y + N.y) * (1.f / 255.f), 0.f);
                e4.z = fmaxf((P.z + N.z) * (1.f / 255.f), 0.f);
                e4.w = fmaxf((P.w + N.w) * (1.f / 255.f), 0.f);
            }
            *reinterpret_cast<float4*>(&sY[rl][k4]) = y4;
            *reinterpret_cast<float4*>(&sE[rl][k4]) = e4;
        }
        __syncthreads();

        float ce = 0.f;
        int hf = tid >> 9, col = tid & 511;
        for (int i = 0; i < 8; ++i) {
            int rl = hf + 2 * i;
            int lr = rl + 1;
            int gy = r0 + rl;
            float y   = sY[lr][col];
            float yu  = sY[lr - 1][col], yd = sY[lr + 1][col];
            float yl  = col        ? sY[lr][col - 1]     : 0.f;
            float yr  = col < 511  ? sY[lr][col + 1]     : 0.f;
            float yul = col        ? sY[lr - 1][col - 1] : 0.f;
            float yur = col < 511  ? sY[lr - 1][col + 1] : 0.f;
            float ydl = col        ? sY[lr + 1][col - 1] : 0.f;
            float ydr = col < 511  ? sY[lr + 1][col + 1] : 0.f;
            float lap = yu + yd + yl + yr - 4.f * y;
            float gx  = (yur + 2.f * yr + ydr) - (yul + 2.f * yl + ydl);
            float gy2 = (ydl + 2.f * yd + ydr) - (yul + 2.f * yu + yur);
            float gm  = sqrtf(gx * gx + gy2 * gy2);
            float e   = sE[lr][col];
            float el  = col       ? sE[lr][col - 1] : 0.f;
            float er  = col < 511 ? sE[lr][col + 1] : 0.f;
            float lapE = sE[lr - 1][col] + sE[lr + 1][col] + el + er - 4.f * e;
            size_t o = (size_t)gy * W512 + col;
            float pn = Pp[o] * (1.f / 255.f);
            float nn = Np[o] * (1.f / 255.f);
            float pb = (pn - nn) * __builtin_amdgcn_rcpf(pn + nn + 1e-12f);
            aY += y; aY2 += y * y; aL += lap; aL2 += lap * lap; aG += gm;
            aPb += pb; aLE += lapE; aLE2 += lapE * lapE; ce += e;
        }
        cellPart[tid] = ce;
        __syncthreads();
        if (tid < 16) {
            float s = 0.f;
            int c0 = tid * 32;
            for (int h2 = 0; h2 < 2; ++h2)
                for (int c = 0; c < 32; ++c) s += cellPart[h2 * 512 + c0 + c];
            if (nb == 1) cellFull[(r0 >> 5) * 16 + tid] += s;
            else         partials[(size_t)blk * 32 + 9 + tid] = s;
        }
        __syncthreads();
    }

    float v[8] = {aY, aY2, aL, aL2, aG, aPb, aLE, aLE2};
    #pragma unroll
    for (int off = 32; off; off >>= 1)
        #pragma unroll
        for (int k = 0; k < 8; ++k) v[k] += __shfl_down(v[k], off);
    int lane = tid & 63, wid = tid >> 6;
    if (lane == 0)
        for (int k = 0; k < 8; ++k) red[wid][k] = v[k];
    __syncthreads();

    if (tid == 0) {
        float s[8];
        for (int k = 0; k < 8; ++k) {
            float t = 0.f;
            for (int w = 0; w < 16; ++w) t += red[w][k];
            s[k] = t;
        }
        if (nb > 1) {
            float* rec = partials + (size_t)blk * 32;
            for (int k = 0; k < 8; ++k) rec[k] = s[k];
        } else {
            float c1 = 0.f, c2 = 0.f, ct = 0.f;
            for (int j = 0; j < 256; ++j) {
                float m = cellFull[j] * (1.f / 1024.f);
                c1 += m; c2 += m * m; ct += cellFull[j];
            }
            const float FN = 262144.f;
            float muY   = s[0] / FN;
            float stdY  = sqrtf(fmaxf(s[1] / FN - muY * muY, 0.f));
            float varlp = fmaxf(s[3] - s[2] * s[2] / FN, 0.f) / (FN - 1.f);
            float gmean = s[4] / FN;
            float mc = c1 * (1.f / 256.f);
            float vc = fmaxf(c2 * (1.f / 256.f) - mc * mc, 0.f);
            float cv = sqrtf(vc) / (mc + 1e-12f);
            float dens = ct / FN;
            float pb = s[5] / FN;
            float varlpE = fmaxf(s[7] - s[6] * s[6] / FN, 0.f) / (FN - 1.f);
            float* zb = z + b * 8;
            zb[0] = muY; zb[1] = stdY; zb[2] = varlp; zb[3] = gmean;
            zb[4] = cv;  zb[5] = dens; zb[6] = pb;    zb[7] = varlpE;
        }
    }
}

// ---------------------------------------------------------------------------
// k_finalize (fast path): merge 32 band records per batch -> z[16][8]
// ---------------------------------------------------------------------------
__global__ __launch_bounds__(256) void k_finalize(
    const float* __restrict__ partials, float* __restrict__ z)
{
    __shared__ float sred[8];
    __shared__ float rr[4][3];
    int b = blockIdx.x, tid = threadIdx.x;
    if (tid < 8) {
        float s = 0.f;
        for (int band = 0; band < 32; ++band)
            s += partials[(size_t)(b * 32 + band) * 32 + tid];
        sred[tid] = s;
    }
    int cr = tid >> 4, cc = tid & 15;
    float cell = partials[(size_t)(b * 32 + 2 * cr)     * 32 + 9 + cc]
               + partials[(size_t)(b * 32 + 2 * cr + 1) * 32 + 9 + cc];
    float m = cell * (1.f / 1024.f);
    float c1 = m, c2 = m * m, ct = cell;
    #pragma unroll
    for (int off = 32; off; off >>= 1) {
        c1 += __shfl_down(c1, off);
        c2 += __shfl_down(c2, off);
        ct += __shfl_down(ct, off);
    }
    int lane = tid & 63, wid = tid >> 6;
    if (lane == 0) { rr[wid][0] = c1; rr[wid][1] = c2; rr[wid][2] = ct; }
    __syncthreads();
    if (tid == 0) {
        float C1 = rr[0][0] + rr[1][0] + rr[2][0] + rr[3][0];
        float C2 = rr[0][1] + rr[1][1] + rr[2][1] + rr[3][1];
        float CT = rr[0][2] + rr[1][2] + rr[2][2] + rr[3][2];
        const float FN = 262144.f;
        float muY   = sred[0] / FN;
        float stdY  = sqrtf(fmaxf(sred[1] / FN - muY * muY, 0.f));
        float varlp = fmaxf(sred[3] - sred[2] * sred[2] / FN, 0.f) / (FN - 1.f);
        float gmean = sred[4] / FN;
        float mc = C1 * (1.f / 256.f);
        float vc = fmaxf(C2 * (1.f / 256.f) - mc * mc, 0.f);
        float cv = sqrtf(vc) / (mc + 1e-12f);
        float dens = CT / FN;
        float pb = sred[5] / FN;
        float varlpE = fmaxf(sred[7] - sred[6] * sred[6] / FN, 0.f) / (FN - 1.f);
        float* zb = z + b * 8;
        zb[0] = muY; zb[1] = stdY; zb[2] = varlp; zb[3] = gmean;
        zb[4] = cv;  zb[5] = dens; zb[6] = pb;    zb[7] = varlpE;
    }
}

// ---------------------------------------------------------------------------
// k_mlp: metrics MLP -> coefs  +  build bf16 MFMA weight fragments in ws.
// K-conventions (shared by A-pack here and B-gather in k_main):
//  conv1: K=32/mfma, k = g*8+j -> tap = m*4+g (>=9 pad0), ic = j (>=5 pad0)
//  conv2: K=32/mfma, k = g*8+j -> tap = 2m+(g>>1) (>=9 pad0), ic=(g&1)*8+j
// A lane&15 = oc row. Biases: b1f separate; conv2 bias folded into cBp.
// ---------------------------------------------------------------------------
__global__ __launch_bounds__(1024) void k_mlp(
    const float* __restrict__ z,
    const float* __restrict__ w1, const float* __restrict__ b1,
    const float* __restrict__ w2, const float* __restrict__ b2,
    const float* __restrict__ hgw, const float* __restrict__ hgb,
    const float* __restrict__ hfw, const float* __restrict__ hfb,
    const float* __restrict__ rs,
    const float* __restrict__ c1w,
    const float* __restrict__ bn1g, const float* __restrict__ bn1b,
    const float* __restrict__ bn1m, const float* __restrict__ bn1v,
    const float* __restrict__ c2w,
    const float* __restrict__ bn2g, const float* __restrict__ bn2b,
    const float* __restrict__ bn2m, const float* __restrict__ bn2v,
    float* __restrict__ coefA, float* __restrict__ cBp,
    u16* __restrict__ w1frag, u16* __restrict__ w2frag,
    float* __restrict__ b1f)
{
    int j = threadIdx.x, b = threadIdx.y;
    int ft = b * 64 + j;   // flat 0..1023

    for (int t = ft; t < 1536; t += 1024) {          // w1frag[m][lane][8]
        int m = t >> 9, ln = (t >> 3) & 63, sl = t & 7;
        int oc = ln & 15, gg = ln >> 4;
        int tap = m * 4 + gg;
        float v = 0.f;
        if (tap < 9 && sl < 5)
            v = c1w[oc * 45 + sl * 9 + tap] * (bn1g[oc] * rsqrtf(bn1v[oc] + 1e-5f));
        w1frag[t] = (u16)f2b_rtne(v);
    }
    for (int t = ft; t < 2560; t += 1024) {          // w2frag[m][lane][8]
        int m = t >> 9, ln = (t >> 3) & 63, sl = t & 7;
        int oc = ln & 15, gg = ln >> 4;
        int tap = 2 * m + (gg >> 1);
        int ic = (gg & 1) * 8 + sl;
        float v = 0.f;
        if (oc < 5 && tap < 9)
            v = c2w[oc * 144 + ic * 9 + tap] * (bn2g[oc] * rsqrtf(bn2v[oc] + 1e-5f));
        w2frag[t] = (u16)f2b_rtne(v);
    }
    if (ft < 16) {
        float inv = bn1g[ft] * rsqrtf(bn1v[ft] + 1e-5f);
        b1f[ft] = bn1b[ft] - bn1m[ft] * inv;
    }

    __shared__ float sZ[16][8], sH1[16][64], sH2[16][64], sG[16][2], sF[16][10];
    if (j < 8) sZ[b][j] = z[b * 8 + j];
    __syncthreads();
    float a = b1[j];
    #pragma unroll
    for (int k = 0; k < 8; ++k) a += sZ[b][k] * w1[j * 8 + k];
    sH1[b][j] = fmaxf(a, 0.f);
    __syncthreads();
    float a2 = b2[j];
    for (int k = 0; k < 64; ++k) a2 += sH1[b][k] * w2[j * 64 + k];
    sH2[b][j] = fmaxf(a2, 0.f);
    __syncthreads();
    if (j < 2) {
        float g = hgb[j];
        for (int k = 0; k < 64; ++k) g += sH2[b][k] * hgw[j * 64 + k];
        sG[b][j] = 1.f / (1.f + __expf(-g));
    }
    if (j < 10) {
        float f = hfb[j];
        for (int k = 0; k < 64; ++k) f += sH2[b][k] * hfw[j * 64 + k];
        sF[b][j] = f;
    }
    __syncthreads();
    if (j < 5) {
        float gs = sG[b][0] + sG[b][1] + 1e-12f;
        float alpha = (j < 2 ? sG[b][0] : sG[b][1]) / gs;
        float gamma = 1.f + 0.1f * sF[b][j];
        float beta  = 0.1f * sF[b][5 + j];
        float r = rs[0];
        float inv2 = bn2g[j] * rsqrtf(bn2v[j] + 1e-5f);
        float b2fold = bn2b[j] - bn2m[j] * inv2;
        float cA = r * alpha * gamma;
        coefA[b * 5 + j] = cA;
        cBp[b * 5 + j]   = r * alpha * beta + cA * b2fold;  // conv2 bias folded
    }
}

// ---------------------------------------------------------------------------
// k_main (MFMA): conv1+bn1+silu+conv2+bn2 + FiLM + residual.
// grid (16,16,16), 256 threads (4 waves), 32x32 tile.
// sIn rows are 40 px wide, aligned to tx0-4 so ALL staging loads are aligned
// float4 and no group ever straddles the image edge (512 % 4 == 0).
// SiLU uses v_rcp (1-ulp) instead of the exact-division sequence.
// ---------------------------------------------------------------------------
__global__ __launch_bounds__(256, 2) void k_main(
    const float* __restrict__ ev, const float* __restrict__ fr,
    const u16* __restrict__ w1frag, const u16* __restrict__ w2frag,
    const float* __restrict__ b1f,
    const float* __restrict__ coefA, const float* __restrict__ cBp,
    float* __restrict__ out)
{
    __shared__ __align__(16) u16 sIn[36 * 40 * 8];    // 23040 B (40 px/row)
    __shared__ __align__(16) u16 sT1[34 * 34 * 24];   // 55488 B

    int tid = threadIdx.x;
    int lane = tid & 63, wv = tid >> 6;
    int g = lane >> 4, col = lane & 15;
    int b = blockIdx.z;
    int ty0 = blockIdx.y * 32, tx0 = blockIdx.x * 32;

    const float* p0 = ev + (size_t)(b * 2)     * HW;
    const float* p1 = ev + (size_t)(b * 2 + 1) * HW;
    const float* p2 = fr + (size_t)(b * 3)     * HW;
    const float* p3 = fr + (size_t)(b * 3 + 1) * HW;
    const float* p4 = fr + (size_t)(b * 3 + 2) * HW;

    // ---- stage sIn: 360 groups of 4 aligned px, channel-minor bf16 ----
    for (int idx = tid; idx < 360; idx += 256) {
        int r = idx / 10, k = idx % 10;
        int gy = ty0 - 2 + r, gx = tx0 - 4 + 4 * k;
        float4 v0 = {0,0,0,0}, v1 = {0,0,0,0}, v2 = {0,0,0,0}, v3 = {0,0,0,0}, v4 = {0,0,0,0};
        if (gy >= 0 && gy < W512 && gx >= 0 && gx < W512) {
            size_t o = (size_t)gy * W512 + gx;
            v0 = *reinterpret_cast<const float4*>(p0 + o);
            v1 = *reinterpret_cast<const float4*>(p1 + o);
            v2 = *reinterpret_cast<const float4*>(p2 + o);
            v3 = *reinterpret_cast<const float4*>(p3 + o);
            v4 = *reinterpret_cast<const float4*>(p4 + o);
        }
        int base = (r * 40 + 4 * k) * 8;
        const float* a0 = (const float*)&v0;
        const float* a1 = (const float*)&v1;
        const float* a2 = (const float*)&v2;
        const float* a3 = (const float*)&v3;
        const float* a4 = (const float*)&v4;
        #pragma unroll
        for (int jx = 0; jx < 4; ++jx) {
            uint4 pk;
            pk.x = pk_bf16(a0[jx], a1[jx]);
            pk.y = pk_bf16(a2[jx], a3[jx]);
            pk.z = pk_bf16(a4[jx], 0.f);
            pk.w = 0;
            *reinterpret_cast<uint4*>(&sIn[base + jx * 8]) = pk;
        }
    }

    // ---- A fragments + per-lane B byte-offsets ----
    short8 a1f[3], a2f[5];
    #pragma unroll
    for (int m = 0; m < 3; ++m)
        a1f[m] = *reinterpret_cast<const short8*>(&w1frag[(m * 64 + lane) * 8]);
    #pragma unroll
    for (int m = 0; m < 5; ++m)
        a2f[m] = *reinterpret_cast<const short8*>(&w2frag[(m * 64 + lane) * 8]);
    f32x4 b1v = *reinterpret_cast<const f32x4*>(&b1f[g * 4]);

    int boff1[3];
    #pragma unroll
    for (int m = 0; m < 3; ++m) {
        int tap = m * 4 + g; if (tap > 8) tap = 8;
        boff1[m] = ((tap / 3) * 40 + (tap % 3)) * 16;
    }
    int boff2[5];
    #pragma unroll
    for (int m = 0; m < 5; ++m) {
        int tap = 2 * m + (g >> 1); if (tap > 8) tap = 8;
        boff2[m] = ((tap / 3) * 34 + (tap % 3)) * 48 + (g & 1) * 16;
    }

    __syncthreads();

    // ---- conv1: 73 N-tiles over 34x34 domain ----
    for (int t = wv; t < 73; t += 4) {
        int q = t * 16 + col;
        int qc = q > 1155 ? 1155 : q;
        int r = qc / 34, c = qc - r * 34;
        const char* base = (const char*)&sIn[(r * 40 + c + 2) * 8];
        f32x4 acc = {0.f, 0.f, 0.f, 0.f};
        #pragma unroll
        for (int m = 0; m < 3; ++m) {
            short8 bf = *reinterpret_cast<const short8*>(base + boff1[m]);
            acc = __builtin_amdgcn_mfma_f32_16x16x32_bf16(a1f[m], bf, acc, 0, 0, 0);
        }
        // bias + silu; zero outside image (conv2 SAME-pads with zeros)
        int gy1 = ty0 - 1 + r, gx1 = tx0 - 1 + c;
        bool inimg = (gy1 >= 0 && gy1 < W512 && gx1 >= 0 && gx1 < W512);
        float v0 = silu_fast(acc[0] + b1v[0]);
        float v1 = silu_fast(acc[1] + b1v[1]);
        float v2 = silu_fast(acc[2] + b1v[2]);
        float v3 = silu_fast(acc[3] + b1v[3]);
        if (!inimg) { v0 = v1 = v2 = v3 = 0.f; }
        if (q <= 1155) {
            uint2 pk;
            pk.x = pk_bf16(v0, v1);
            pk.y = pk_bf16(v2, v3);
            *reinterpret_cast<uint2*>(&sT1[(r * 34 + c) * 24 + g * 4]) = pk;
        }
    }
    __syncthreads();

    // ---- conv2 + epilogue: 64 N-tiles over 32x32 ----
    float cA0 = coefA[b * 5 + 0], cA1 = coefA[b * 5 + 1], cA2 = coefA[b * 5 + 2];
    float cA3 = coefA[b * 5 + 3], cA4 = coefA[b * 5 + 4];
    float cB0 = cBp[b * 5 + 0], cB1 = cBp[b * 5 + 1], cB2 = cBp[b * 5 + 2];
    float cB3 = cBp[b * 5 + 3], cB4 = cBp[b * 5 + 4];
    const size_t OUT2 = (size_t)32 * HW;

    for (int t = wv; t < 64; t += 4) {
        int q = t * 16 + col;
        int r = q >> 5, c = q & 31;
        const char* base = (const char*)&sT1[(r * 34 + c) * 24];
        f32x4 acc = {0.f, 0.f, 0.f, 0.f};
        #pragma unroll
        for (int m = 0; m < 5; ++m) {
            short8 bf = *reinterpret_cast<const short8*>(base + boff2[m]);
            acc = __builtin_amdgcn_mfma_f32_16x16x32_bf16(a2f[m], bf, acc, 0, 0, 0);
        }
        size_t px = (size_t)(ty0 + r) * W512 + (tx0 + c);
        if (g == 0) {   // oc 0..3
            out[(size_t)(b * 2 + 0) * HW + px] = p0[px] + cA0 * acc[0] + cB0;
            out[(size_t)(b * 2 + 1) * HW + px] = p1[px] + cA1 * acc[1] + cB1;
            out[OUT2 + (size_t)(b * 3 + 0) * HW + px] = p2[px] + cA2 * acc[2] + cB2;
            out[OUT2 + (size_t)(b * 3 + 1) * HW + px] = p3[px] + cA3 * acc[3] + cB3;
        } else if (g == 1) {   // oc 4
            out[OUT2 + (size_t)(b * 3 + 2) * HW + px] = p4[px] + cA4 * acc[0] + cB4;
        }
    }
}

// ---------------------------------------------------------------------------
extern "C" void kernel_launch(void* const* d_in, const int* in_sizes, int n_in,
                              void* d_out, int out_size, void* d_ws, size_t ws_size,
                              hipStream_t stream)
{
    const float* ev = (const float*)d_in[0];
    const float* fr = (const float*)d_in[1];

    char* wb = (char*)d_ws;
    float* coefA    = (float*)(wb + 0);      // 80 f
    float* cBp      = (float*)(wb + 320);    // 80 f
    float* b1f      = (float*)(wb + 640);    // 16 f
    u16*   w1frag   = (u16*) (wb + 768);     // 1536 u16
    u16*   w2frag   = (u16*) (wb + 3840);    // 2560 u16
    float* zbuf     = (float*)(wb + 8960);   // 128 f
    float* partials = (float*)(wb + 10240);  // 16384 f  -> total 75776 B

    bool fast = (ws_size >= 75776);
    int nb   = fast ? 32 : 1;
    int nblk = fast ? 512 : 16;
    k_band<<<dim3(nblk), dim3(1024), 0, stream>>>(ev, fr, nb, partials, zbuf);
    if (fast) k_finalize<<<dim3(16), dim3(256), 0, stream>>>(partials, zbuf);

    k_mlp<<<dim3(1), dim3(64, 16), 0, stream>>>(zbuf,
        (const float*)d_in[12], (const float*)d_in[13], (const float*)d_in[14], (const float*)d_in[15],
        (const float*)d_in[16], (const float*)d_in[17], (const float*)d_in[18], (const float*)d_in[19],
        (const float*)d_in[20],
        (const float*)d_in[2], (const float*)d_in[3], (const float*)d_in[4], (const float*)d_in[5],
        (const float*)d_in[6], (const float*)d_in[7], (const float*)d_in[8], (const float*)d_in[9],
        (const float*)d_in[10], (const float*)d_in[11],
        coefA, cBp, w1frag, w2frag, b1f);

    k_main<<<dim3(16, 16, 16), dim3(256), 0, stream>>>(ev, fr,
        w1frag, w2frag, b1f, coefA, cBp, (float*)d_out);
}

// Round 12
// 149.864 us; speedup vs baseline: 2.4816x; 1.3725x over previous
//
#include <hip/hip_runtime.h>
#include <hip/hip_bf16.h>

typedef unsigned int   u32;
typedef unsigned short u16;

#define HW 262144   // 512*512
#define W512 512

typedef __attribute__((ext_vector_type(8))) short short8;   // 8 bf16 (4 VGPRs)
typedef __attribute__((ext_vector_type(4))) float f32x4;

__device__ __forceinline__ u32 f2b_rtne(float f) {   // f32 -> bf16 bits (RTNE)
    union { float f; u32 i; } c; c.f = f;
    u32 u = c.i;
    return (u + 0x7FFFu + ((u >> 16) & 1u)) >> 16;
}
__device__ __forceinline__ u32 pk_bf16(float lo, float hi) {  // 2xf32 -> packed bf16 pair
    float2 t; t.x = lo; t.y = hi;
    __hip_bfloat162 h = __float22bfloat162_rn(t);
    return *reinterpret_cast<u32*>(&h);
}
__device__ __forceinline__ float lo16(u32 w) {
    union { u32 i; float f; } c; c.i = w << 16; return c.f;
}
__device__ __forceinline__ float hi16(u32 w) {
    union { u32 i; float f; } c; c.i = w & 0xFFFF0000u; return c.f;
}
__device__ __forceinline__ float silu_fast(float v) {
    return v * __builtin_amdgcn_rcpf(1.f + __expf(-v));
}

// load 6 consecutive bf16 values [c4-1 .. c4+4] from a padded row (base = 8+c4)
__device__ __forceinline__ void row6(const u16* rowp, int base, float* o) {
    uint2 A = *reinterpret_cast<const uint2*>(rowp + base - 4);
    uint2 B = *reinterpret_cast<const uint2*>(rowp + base);
    uint2 C = *reinterpret_cast<const uint2*>(rowp + base + 4);
    o[0] = hi16(A.y);
    o[1] = lo16(B.x); o[2] = hi16(B.x);
    o[3] = lo16(B.y); o[4] = hi16(B.y);
    o[5] = lo16(C.x);
}

// ---------------------------------------------------------------------------
// k_band: metrics over a horizontal band. nb bands/batch (32 fast, 1 slow).
// bf16 stencil tiles with 8-col zero pad (no edge branches); b64 quad reads;
// pb-sum folded into the staging pass (no P/N re-reads).
// ---------------------------------------------------------------------------
__global__ __launch_bounds__(1024) void k_band(
    const float* __restrict__ ev, const float* __restrict__ fr,
    int nb, float* __restrict__ partials, float* __restrict__ z)
{
    __shared__ u16 sYb[18][528];   // bf16, data at cols 8..519
    __shared__ u16 sEb[18][528];
    __shared__ float cellPart[1024];
    __shared__ float cellFull[256];
    __shared__ float red[16][8];

    int blk = blockIdx.x;
    int b = blk / nb, band = blk % nb;
    int rowsPerBand = 512 / nb;
    int chunks = rowsPerBand >> 4;
    int rBase = band * rowsPerBand;
    int tid = threadIdx.x;

    const float* Pp = ev + (size_t)(b * 2)     * HW;
    const float* Np = ev + (size_t)(b * 2 + 1) * HW;
    const float* Rp = fr + (size_t)(b * 3)     * HW;
    const float* Gp = fr + (size_t)(b * 3 + 1) * HW;
    const float* Bp = fr + (size_t)(b * 3 + 2) * HW;

    if (nb == 1 && tid < 256) cellFull[tid] = 0.f;
    // zero the padded columns once (16B per row side)
    if (tid < 36) {
        int rr = tid >> 1, side = tid & 1;
        uint4 zz = {0, 0, 0, 0};
        *reinterpret_cast<uint4*>(&sYb[rr][side ? 520 : 0]) = zz;
        *reinterpret_cast<uint4*>(&sEb[rr][side ? 520 : 0]) = zz;
    }

    float aY = 0, aY2 = 0, aL = 0, aL2 = 0, aG = 0, aPb = 0, aLE = 0, aLE2 = 0;

    for (int ch = 0; ch < chunks; ++ch) {
        int r0 = rBase + ch * 16;
        __syncthreads();   // pads zeroed / previous compute done
        // stage 18 rows x 128 quads; accumulate pb for interior rows
        for (int idx = tid; idx < 2304; idx += 1024) {
            int rl = idx >> 7, q4 = (idx & 127) << 2;
            int gy = r0 - 1 + rl;
            float4 y4 = {0.f, 0.f, 0.f, 0.f};
            float4 e4 = {0.f, 0.f, 0.f, 0.f};
            if (gy >= 0 && gy < W512) {
                size_t o = (size_t)gy * W512 + q4;
                float4 R = *reinterpret_cast<const float4*>(Rp + o);
                float4 G = *reinterpret_cast<const float4*>(Gp + o);
                float4 B = *reinterpret_cast<const float4*>(Bp + o);
                float4 P = *reinterpret_cast<const float4*>(Pp + o);
                float4 N = *reinterpret_cast<const float4*>(Np + o);
                y4.x = fminf(fmaxf(0.299f * R.x + 0.587f * G.x + 0.114f * B.x, 0.f), 1.f);
                y4.y = fminf(fmaxf(0.299f * R.y + 0.587f * G.y + 0.114f * B.y, 0.f), 1.f);
                y4.z = fminf(fmaxf(0.299f * R.z + 0.587f * G.z + 0.114f * B.z, 0.f), 1.f);
                y4.w = fminf(fmaxf(0.299f * R.w + 0.587f * G.w + 0.114f * B.w, 0.f), 1.f);
                e4.x = fmaxf((P.x + N.x) * (1.f / 255.f), 0.f);
                e4.y = fmaxf((P.y + N.y) * (1.f / 255.f), 0.f);
                e4.z = fmaxf((P.z + N.z) * (1.f / 255.f), 0.f);
                e4.w = fmaxf((P.w + N.w) * (1.f / 255.f), 0.f);
                if (rl >= 1 && rl <= 16) {   // interior: accumulate pb here
                    float pnx = P.x * (1.f / 255.f), nnx = N.x * (1.f / 255.f);
                    float pny = P.y * (1.f / 255.f), nny = N.y * (1.f / 255.f);
                    float pnz = P.z * (1.f / 255.f), nnz = N.z * (1.f / 255.f);
                    float pnw = P.w * (1.f / 255.f), nnw = N.w * (1.f / 255.f);
                    aPb += (pnx - nnx) * __builtin_amdgcn_rcpf(pnx + nnx + 1e-12f);
                    aPb += (pny - nny) * __builtin_amdgcn_rcpf(pny + nny + 1e-12f);
                    aPb += (pnz - nnz) * __builtin_amdgcn_rcpf(pnz + nnz + 1e-12f);
                    aPb += (pnw - nnw) * __builtin_amdgcn_rcpf(pnw + nnw + 1e-12f);
                }
            }
            uint2 py, pe;
            py.x = pk_bf16(y4.x, y4.y); py.y = pk_bf16(y4.z, y4.w);
            pe.x = pk_bf16(e4.x, e4.y); pe.y = pk_bf16(e4.z, e4.w);
            *reinterpret_cast<uint2*>(&sYb[rl][8 + q4]) = py;
            *reinterpret_cast<uint2*>(&sEb[rl][8 + q4]) = pe;
        }
        __syncthreads();

        float ce = 0.f;
        #pragma unroll
        for (int q = 0; q < 2; ++q) {
            int qi = tid + (q << 10);
            int row = qi >> 7, c4 = (qi & 127) << 2;
            int lr = row + 1, base = 8 + c4;
            float y0[6], y1[6], y2[6], er[6];
            row6(&sYb[lr - 1][0], base, y0);
            row6(&sYb[lr][0],     base, y1);
            row6(&sYb[lr + 1][0], base, y2);
            row6(&sEb[lr][0],     base, er);
            uint2 U = *reinterpret_cast<const uint2*>(&sEb[lr - 1][base]);
            uint2 D = *reinterpret_cast<const uint2*>(&sEb[lr + 1][base]);
            float eu[4] = {lo16(U.x), hi16(U.x), lo16(U.y), hi16(U.y)};
            float ed[4] = {lo16(D.x), hi16(D.x), lo16(D.y), hi16(D.y)};
            #pragma unroll
            for (int j = 0; j < 4; ++j) {
                float y = y1[j + 1];
                float lap = y0[j + 1] + y2[j + 1] + y1[j] + y1[j + 2] - 4.f * y;
                float gx  = (y0[j + 2] + 2.f * y1[j + 2] + y2[j + 2])
                          - (y0[j]     + 2.f * y1[j]     + y2[j]);
                float gy2 = (y2[j] + 2.f * y2[j + 1] + y2[j + 2])
                          - (y0[j] + 2.f * y0[j + 1] + y0[j + 2]);
                float gm = sqrtf(gx * gx + gy2 * gy2);
                float e = er[j + 1];
                float lapE = eu[j] + ed[j] + er[j] + er[j + 2] - 4.f * e;
                aY += y; aY2 += y * y; aL += lap; aL2 += lap * lap; aG += gm;
                aLE += lapE; aLE2 += lapE * lapE; ce += e;
            }
        }
        cellPart[tid] = ce;
        __syncthreads();
        if (tid < 16) {   // cell tid = cols 32*tid..32*tid+31, fixed order
            float s = 0.f;
            for (int rg = 0; rg < 8; ++rg)
                for (int k = 0; k < 8; ++k)
                    s += cellPart[rg * 128 + tid * 8 + k];
            if (nb == 1) cellFull[(r0 >> 5) * 16 + tid] += s;
            else         partials[(size_t)blk * 32 + 9 + tid] = s;
        }
    }
    __syncthreads();

    float v[8] = {aY, aY2, aL, aL2, aG, aPb, aLE, aLE2};
    #pragma unroll
    for (int off = 32; off; off >>= 1)
        #pragma unroll
        for (int k = 0; k < 8; ++k) v[k] += __shfl_down(v[k], off);
    int lane = tid & 63, wid = tid >> 6;
    if (lane == 0)
        for (int k = 0; k < 8; ++k) red[wid][k] = v[k];
    __syncthreads();

    if (tid == 0) {
        float s[8];
        for (int k = 0; k < 8; ++k) {
            float t = 0.f;
            for (int w = 0; w < 16; ++w) t += red[w][k];
            s[k] = t;
        }
        if (nb > 1) {
            float* rec = partials + (size_t)blk * 32;
            for (int k = 0; k < 8; ++k) rec[k] = s[k];
        } else {
            float c1 = 0.f, c2 = 0.f, ct = 0.f;
            for (int j = 0; j < 256; ++j) {
                float m = cellFull[j] * (1.f / 1024.f);
                c1 += m; c2 += m * m; ct += cellFull[j];
            }
            const float FN = 262144.f;
            float muY   = s[0] / FN;
            float stdY  = sqrtf(fmaxf(s[1] / FN - muY * muY, 0.f));
            float varlp = fmaxf(s[3] - s[2] * s[2] / FN, 0.f) / (FN - 1.f);
            float gmean = s[4] / FN;
            float mc = c1 * (1.f / 256.f);
            float vc = fmaxf(c2 * (1.f / 256.f) - mc * mc, 0.f);
            float cv = sqrtf(vc) / (mc + 1e-12f);
            float dens = ct / FN;
            float pb = s[5] / FN;
            float varlpE = fmaxf(s[7] - s[6] * s[6] / FN, 0.f) / (FN - 1.f);
            float* zb = z + b * 8;
            zb[0] = muY; zb[1] = stdY; zb[2] = varlp; zb[3] = gmean;
            zb[4] = cv;  zb[5] = dens; zb[6] = pb;    zb[7] = varlpE;
        }
    }
}

// ---------------------------------------------------------------------------
// k_finalize (fast path): merge 32 band records per batch -> z[16][8]
// ---------------------------------------------------------------------------
__global__ __launch_bounds__(256) void k_finalize(
    const float* __restrict__ partials, float* __restrict__ z)
{
    __shared__ float sred[8];
    __shared__ float rr[4][3];
    int b = blockIdx.x, tid = threadIdx.x;
    if (tid < 8) {
        float s = 0.f;
        for (int band = 0; band < 32; ++band)
            s += partials[(size_t)(b * 32 + band) * 32 + tid];
        sred[tid] = s;
    }
    int cr = tid >> 4, cc = tid & 15;
    float cell = partials[(size_t)(b * 32 + 2 * cr)     * 32 + 9 + cc]
               + partials[(size_t)(b * 32 + 2 * cr + 1) * 32 + 9 + cc];
    float m = cell * (1.f / 1024.f);
    float c1 = m, c2 = m * m, ct = cell;
    #pragma unroll
    for (int off = 32; off; off >>= 1) {
        c1 += __shfl_down(c1, off);
        c2 += __shfl_down(c2, off);
        ct += __shfl_down(ct, off);
    }
    int lane = tid & 63, wid = tid >> 6;
    if (lane == 0) { rr[wid][0] = c1; rr[wid][1] = c2; rr[wid][2] = ct; }
    __syncthreads();
    if (tid == 0) {
        float C1 = rr[0][0] + rr[1][0] + rr[2][0] + rr[3][0];
        float C2 = rr[0][1] + rr[1][1] + rr[2][1] + rr[3][1];
        float CT = rr[0][2] + rr[1][2] + rr[2][2] + rr[3][2];
        const float FN = 262144.f;
        float muY   = sred[0] / FN;
        float stdY  = sqrtf(fmaxf(sred[1] / FN - muY * muY, 0.f));
        float varlp = fmaxf(sred[3] - sred[2] * sred[2] / FN, 0.f) / (FN - 1.f);
        float gmean = sred[4] / FN;
        float mc = C1 * (1.f / 256.f);
        float vc = fmaxf(C2 * (1.f / 256.f) - mc * mc, 0.f);
        float cv = sqrtf(vc) / (mc + 1e-12f);
        float dens = CT / FN;
        float pb = sred[5] / FN;
        float varlpE = fmaxf(sred[7] - sred[6] * sred[6] / FN, 0.f) / (FN - 1.f);
        float* zb = z + b * 8;
        zb[0] = muY; zb[1] = stdY; zb[2] = varlp; zb[3] = gmean;
        zb[4] = cv;  zb[5] = dens; zb[6] = pb;    zb[7] = varlpE;
    }
}

// ---------------------------------------------------------------------------
// k_mlp: metrics MLP -> coefs  +  build bf16 MFMA weight fragments in ws.
// K-conventions (shared by A-pack here and B-gather in k_main):
//  conv1: K=32/mfma, k = g*8+j -> tap = m*4+g (>=9 pad0), ic = j (>=5 pad0)
//  conv2: K=32/mfma, k = g*8+j -> tap = 2m+(g>>1) (>=9 pad0), ic=(g&1)*8+j
// A lane&15 = oc row. Biases: b1f separate; conv2 bias folded into cBp.
// ---------------------------------------------------------------------------
__global__ __launch_bounds__(1024) void k_mlp(
    const float* __restrict__ z,
    const float* __restrict__ w1, const float* __restrict__ b1,
    const float* __restrict__ w2, const float* __restrict__ b2,
    const float* __restrict__ hgw, const float* __restrict__ hgb,
    const float* __restrict__ hfw, const float* __restrict__ hfb,
    const float* __restrict__ rs,
    const float* __restrict__ c1w,
    const float* __restrict__ bn1g, const float* __restrict__ bn1b,
    const float* __restrict__ bn1m, const float* __restrict__ bn1v,
    const float* __restrict__ c2w,
    const float* __restrict__ bn2g, const float* __restrict__ bn2b,
    const float* __restrict__ bn2m, const float* __restrict__ bn2v,
    float* __restrict__ coefA, float* __restrict__ cBp,
    u16* __restrict__ w1frag, u16* __restrict__ w2frag,
    float* __restrict__ b1f)
{
    int j = threadIdx.x, b = threadIdx.y;
    int ft = b * 64 + j;   // flat 0..1023

    for (int t = ft; t < 1536; t += 1024) {          // w1frag[m][lane][8]
        int m = t >> 9, ln = (t >> 3) & 63, sl = t & 7;
        int oc = ln & 15, gg = ln >> 4;
        int tap = m * 4 + gg;
        float v = 0.f;
        if (tap < 9 && sl < 5)
            v = c1w[oc * 45 + sl * 9 + tap] * (bn1g[oc] * rsqrtf(bn1v[oc] + 1e-5f));
        w1frag[t] = (u16)f2b_rtne(v);
    }
    for (int t = ft; t < 2560; t += 1024) {          // w2frag[m][lane][8]
        int m = t >> 9, ln = (t >> 3) & 63, sl = t & 7;
        int oc = ln & 15, gg = ln >> 4;
        int tap = 2 * m + (gg >> 1);
        int ic = (gg & 1) * 8 + sl;
        float v = 0.f;
        if (oc < 5 && tap < 9)
            v = c2w[oc * 144 + ic * 9 + tap] * (bn2g[oc] * rsqrtf(bn2v[oc] + 1e-5f));
        w2frag[t] = (u16)f2b_rtne(v);
    }
    if (ft < 16) {
        float inv = bn1g[ft] * rsqrtf(bn1v[ft] + 1e-5f);
        b1f[ft] = bn1b[ft] - bn1m[ft] * inv;
    }

    __shared__ float sZ[16][8], sH1[16][64], sH2[16][64], sG[16][2], sF[16][10];
    if (j < 8) sZ[b][j] = z[b * 8 + j];
    __syncthreads();
    float a = b1[j];
    #pragma unroll
    for (int k = 0; k < 8; ++k) a += sZ[b][k] * w1[j * 8 + k];
    sH1[b][j] = fmaxf(a, 0.f);
    __syncthreads();
    float a2 = b2[j];
    for (int k = 0; k < 64; ++k) a2 += sH1[b][k] * w2[j * 64 + k];
    sH2[b][j] = fmaxf(a2, 0.f);
    __syncthreads();
    if (j < 2) {
        float g = hgb[j];
        for (int k = 0; k < 64; ++k) g += sH2[b][k] * hgw[j * 64 + k];
        sG[b][j] = 1.f / (1.f + __expf(-g));
    }
    if (j < 10) {
        float f = hfb[j];
        for (int k = 0; k < 64; ++k) f += sH2[b][k] * hfw[j * 64 + k];
        sF[b][j] = f;
    }
    __syncthreads();
    if (j < 5) {
        float gs = sG[b][0] + sG[b][1] + 1e-12f;
        float alpha = (j < 2 ? sG[b][0] : sG[b][1]) / gs;
        float gamma = 1.f + 0.1f * sF[b][j];
        float beta  = 0.1f * sF[b][5 + j];
        float r = rs[0];
        float inv2 = bn2g[j] * rsqrtf(bn2v[j] + 1e-5f);
        float b2fold = bn2b[j] - bn2m[j] * inv2;
        float cA = r * alpha * gamma;
        coefA[b * 5 + j] = cA;
        cBp[b * 5 + j]   = r * alpha * beta + cA * b2fold;  // conv2 bias folded
    }
}

// ---------------------------------------------------------------------------
// k_main (MFMA): conv1+bn1+silu+conv2+bn2 + FiLM + residual.
// grid (16,32,16) = 32x16 tiles, 256 threads (4 waves).
// LDS 42.2 KB -> 3 blocks/CU (12 waves) for latency hiding.
// ---------------------------------------------------------------------------
__global__ __launch_bounds__(256, 3) void k_main(
    const float* __restrict__ ev, const float* __restrict__ fr,
    const u16* __restrict__ w1frag, const u16* __restrict__ w2frag,
    const float* __restrict__ b1f,
    const float* __restrict__ coefA, const float* __restrict__ cBp,
    float* __restrict__ out)
{
    __shared__ __align__(16) u16 sIn[20 * 40 * 8];    // 12800 B
    __shared__ __align__(16) u16 sT1[18 * 34 * 24];   // 29376 B

    int tid = threadIdx.x;
    int lane = tid & 63, wv = tid >> 6;
    int g = lane >> 4, col = lane & 15;
    int b = blockIdx.z;
    int ty0 = blockIdx.y * 16, tx0 = blockIdx.x * 32;

    const float* p0 = ev + (size_t)(b * 2)     * HW;
    const float* p1 = ev + (size_t)(b * 2 + 1) * HW;
    const float* p2 = fr + (size_t)(b * 3)     * HW;
    const float* p3 = fr + (size_t)(b * 3 + 1) * HW;
    const float* p4 = fr + (size_t)(b * 3 + 2) * HW;

    // ---- stage sIn: 200 groups of 4 aligned px, channel-minor bf16 ----
    if (tid < 200) {
        int r = tid / 10, k = tid % 10;
        int gy = ty0 - 2 + r, gx = tx0 - 4 + 4 * k;
        float4 v0 = {0,0,0,0}, v1 = {0,0,0,0}, v2 = {0,0,0,0}, v3 = {0,0,0,0}, v4 = {0,0,0,0};
        if (gy >= 0 && gy < W512 && gx >= 0 && gx < W512) {
            size_t o = (size_t)gy * W512 + gx;
            v0 = *reinterpret_cast<const float4*>(p0 + o);
            v1 = *reinterpret_cast<const float4*>(p1 + o);
            v2 = *reinterpret_cast<const float4*>(p2 + o);
            v3 = *reinterpret_cast<const float4*>(p3 + o);
            v4 = *reinterpret_cast<const float4*>(p4 + o);
        }
        int base = (r * 40 + 4 * k) * 8;
        const float* a0 = (const float*)&v0;
        const float* a1 = (const float*)&v1;
        const float* a2 = (const float*)&v2;
        const float* a3 = (const float*)&v3;
        const float* a4 = (const float*)&v4;
        #pragma unroll
        for (int jx = 0; jx < 4; ++jx) {
            uint4 pk;
            pk.x = pk_bf16(a0[jx], a1[jx]);
            pk.y = pk_bf16(a2[jx], a3[jx]);
            pk.z = pk_bf16(a4[jx], 0.f);
            pk.w = 0;
            *reinterpret_cast<uint4*>(&sIn[base + jx * 8]) = pk;
        }
    }

    // ---- A fragments + per-lane B byte-offsets ----
    short8 a1f[3], a2f[5];
    #pragma unroll
    for (int m = 0; m < 3; ++m)
        a1f[m] = *reinterpret_cast<const short8*>(&w1frag[(m * 64 + lane) * 8]);
    #pragma unroll
    for (int m = 0; m < 5; ++m)
        a2f[m] = *reinterpret_cast<const short8*>(&w2frag[(m * 64 + lane) * 8]);
    f32x4 b1v = *reinterpret_cast<const f32x4*>(&b1f[g * 4]);

    int boff1[3];
    #pragma unroll
    for (int m = 0; m < 3; ++m) {
        int tap = m * 4 + g; if (tap > 8) tap = 8;
        boff1[m] = ((tap / 3) * 40 + (tap % 3)) * 16;
    }
    int boff2[5];
    #pragma unroll
    for (int m = 0; m < 5; ++m) {
        int tap = 2 * m + (g >> 1); if (tap > 8) tap = 8;
        boff2[m] = ((tap / 3) * 34 + (tap % 3)) * 48 + (g & 1) * 16;
    }

    __syncthreads();

    // ---- conv1: 39 N-tiles over 18x34 domain (611 = last px, clamp-dup) ----
    for (int t = wv; t < 39; t += 4) {
        int q = t * 16 + col;
        int qc = q > 611 ? 611 : q;
        int r = qc / 34, c = qc - r * 34;
        const char* base = (const char*)&sIn[(r * 40 + c + 2) * 8];
        f32x4 acc = {0.f, 0.f, 0.f, 0.f};
        #pragma unroll
        for (int m = 0; m < 3; ++m) {
            short8 bf = *reinterpret_cast<const short8*>(base + boff1[m]);
            acc = __builtin_amdgcn_mfma_f32_16x16x32_bf16(a1f[m], bf, acc, 0, 0, 0);
        }
        int gy1 = ty0 - 1 + r, gx1 = tx0 - 1 + c;
        bool inimg = (gy1 >= 0 && gy1 < W512 && gx1 >= 0 && gx1 < W512);
        float v0 = silu_fast(acc[0] + b1v[0]);
        float v1 = silu_fast(acc[1] + b1v[1]);
        float v2 = silu_fast(acc[2] + b1v[2]);
        float v3 = silu_fast(acc[3] + b1v[3]);
        if (!inimg) { v0 = v1 = v2 = v3 = 0.f; }
        uint2 pk;
        pk.x = pk_bf16(v0, v1);
        pk.y = pk_bf16(v2, v3);
        *reinterpret_cast<uint2*>(&sT1[(r * 34 + c) * 24 + g * 4]) = pk;
    }
    __syncthreads();

    // ---- conv2 + epilogue: 32 N-tiles over 32x16 ----
    float cA0 = coefA[b * 5 + 0], cA1 = coefA[b * 5 + 1], cA2 = coefA[b * 5 + 2];
    float cA3 = coefA[b * 5 + 3], cA4 = coefA[b * 5 + 4];
    float cB0 = cBp[b * 5 + 0], cB1 = cBp[b * 5 + 1], cB2 = cBp[b * 5 + 2];
    float cB3 = cBp[b * 5 + 3], cB4 = cBp[b * 5 + 4];
    const size_t OUT2 = (size_t)32 * HW;

    for (int t = wv; t < 32; t += 4) {
        int q = t * 16 + col;
        int r = q >> 5, c = q & 31;
        const char* base = (const char*)&sT1[(r * 34 + c) * 24];
        f32x4 acc = {0.f, 0.f, 0.f, 0.f};
        #pragma unroll
        for (int m = 0; m < 5; ++m) {
            short8 bf = *reinterpret_cast<const short8*>(base + boff2[m]);
            acc = __builtin_amdgcn_mfma_f32_16x16x32_bf16(a2f[m], bf, acc, 0, 0, 0);
        }
        size_t px = (size_t)(ty0 + r) * W512 + (tx0 + c);
        if (g == 0) {   // oc 0..3
            out[(size_t)(b * 2 + 0) * HW + px] = p0[px] + cA0 * acc[0] + cB0;
            out[(size_t)(b * 2 + 1) * HW + px] = p1[px] + cA1 * acc[1] + cB1;
            out[OUT2 + (size_t)(b * 3 + 0) * HW + px] = p2[px] + cA2 * acc[2] + cB2;
            out[OUT2 + (size_t)(b * 3 + 1) * HW + px] = p3[px] + cA3 * acc[3] + cB3;
        } else if (g == 1) {   // oc 4
            out[OUT2 + (size_t)(b * 3 + 2) * HW + px] = p4[px] + cA4 * acc[0] + cB4;
        }
    }
}

// ---------------------------------------------------------------------------
extern "C" void kernel_launch(void* const* d_in, const int* in_sizes, int n_in,
                              void* d_out, int out_size, void* d_ws, size_t ws_size,
                              hipStream_t stream)
{
    const float* ev = (const float*)d_in[0];
    const float* fr = (const float*)d_in[1];

    char* wb = (char*)d_ws;
    float* coefA    = (float*)(wb + 0);      // 80 f
    float* cBp      = (float*)(wb + 320);    // 80 f
    float* b1f      = (float*)(wb + 640);    // 16 f
    u16*   w1frag   = (u16*) (wb + 768);     // 1536 u16
    u16*   w2frag   = (u16*) (wb + 3840);    // 2560 u16
    float* zbuf     = (float*)(wb + 8960);   // 128 f
    float* partials = (float*)(wb + 10240);  // 16384 f  -> total 75776 B

    bool fast = (ws_size >= 75776);
    int nb   = fast ? 32 : 1;
    int nblk = fast ? 512 : 16;
    k_band<<<dim3(nblk), dim3(1024), 0, stream>>>(ev, fr, nb, partials, zbuf);
    if (fast) k_finalize<<<dim3(16), dim3(256), 0, stream>>>(partials, zbuf);

    k_mlp<<<dim3(1), dim3(64, 16), 0, stream>>>(zbuf,
        (const float*)d_in[12], (const float*)d_in[13], (const float*)d_in[14], (const float*)d_in[15],
        (const float*)d_in[16], (const float*)d_in[17], (const float*)d_in[18], (const float*)d_in[19],
        (const float*)d_in[20],
        (const float*)d_in[2], (const float*)d_in[3], (const float*)d_in[4], (const float*)d_in[5],
        (const float*)d_in[6], (const float*)d_in[7], (const float*)d_in[8], (const float*)d_in[9],
        (const float*)d_in[10], (const float*)d_in[11],
        coefA, cBp, w1frag, w2frag, b1f);

    k_main<<<dim3(16, 32, 16), dim3(256), 0, stream>>>(ev, fr,
        w1frag, w2frag, b1f, coefA, cBp, (float*)d_out);
}

// Round 13
// 140.720 us; speedup vs baseline: 2.6428x; 1.0650x over previous
//
#include <hip/hip_runtime.h>
#include <hip/hip_bf16.h>

typedef unsigned int   u32;
typedef unsigned short u16;

#define HW 262144   // 512*512
#define W512 512

typedef __attribute__((ext_vector_type(8))) short short8;   // 8 bf16 (4 VGPRs)
typedef __attribute__((ext_vector_type(4))) float f32x4;

__device__ __forceinline__ u32 f2b_rtne(float f) {   // f32 -> bf16 bits (RTNE)
    union { float f; u32 i; } c; c.f = f;
    u32 u = c.i;
    return (u + 0x7FFFu + ((u >> 16) & 1u)) >> 16;
}
__device__ __forceinline__ u32 pk_bf16(float lo, float hi) {  // 2xf32 -> packed bf16 pair
    float2 t; t.x = lo; t.y = hi;
    __hip_bfloat162 h = __float22bfloat162_rn(t);
    return *reinterpret_cast<u32*>(&h);
}
__device__ __forceinline__ float lo16(u32 w) {
    union { u32 i; float f; } c; c.i = w << 16; return c.f;
}
__device__ __forceinline__ float hi16(u32 w) {
    union { u32 i; float f; } c; c.i = w & 0xFFFF0000u; return c.f;
}
__device__ __forceinline__ float silu_fast(float v) {
    return v * __builtin_amdgcn_rcpf(1.f + __expf(-v));
}

// load 6 consecutive bf16 values [c4-1 .. c4+4] from a padded row (base = 8+c4)
__device__ __forceinline__ void row6(const u16* rowp, int base, float* o) {
    uint2 A = *reinterpret_cast<const uint2*>(rowp + base - 4);
    uint2 B = *reinterpret_cast<const uint2*>(rowp + base);
    uint2 C = *reinterpret_cast<const uint2*>(rowp + base + 4);
    o[0] = hi16(A.y);
    o[1] = lo16(B.x); o[2] = hi16(B.x);
    o[3] = lo16(B.y); o[4] = hi16(B.y);
    o[5] = lo16(C.x);
}

// ---------------------------------------------------------------------------
// k_band: metrics over a horizontal band. nb bands/batch (32 fast, 1 slow).
// ---------------------------------------------------------------------------
__global__ __launch_bounds__(1024) void k_band(
    const float* __restrict__ ev, const float* __restrict__ fr,
    int nb, float* __restrict__ partials, float* __restrict__ z)
{
    __shared__ u16 sYb[18][528];   // bf16, data at cols 8..519
    __shared__ u16 sEb[18][528];
    __shared__ float cellPart[1024];
    __shared__ float cellFull[256];
    __shared__ float red[16][8];

    int blk = blockIdx.x;
    int b = blk / nb, band = blk % nb;
    int rowsPerBand = 512 / nb;
    int chunks = rowsPerBand >> 4;
    int rBase = band * rowsPerBand;
    int tid = threadIdx.x;

    const float* Pp = ev + (size_t)(b * 2)     * HW;
    const float* Np = ev + (size_t)(b * 2 + 1) * HW;
    const float* Rp = fr + (size_t)(b * 3)     * HW;
    const float* Gp = fr + (size_t)(b * 3 + 1) * HW;
    const float* Bp = fr + (size_t)(b * 3 + 2) * HW;

    if (nb == 1 && tid < 256) cellFull[tid] = 0.f;
    if (tid < 36) {
        int rr = tid >> 1, side = tid & 1;
        uint4 zz = {0, 0, 0, 0};
        *reinterpret_cast<uint4*>(&sYb[rr][side ? 520 : 0]) = zz;
        *reinterpret_cast<uint4*>(&sEb[rr][side ? 520 : 0]) = zz;
    }

    float aY = 0, aY2 = 0, aL = 0, aL2 = 0, aG = 0, aPb = 0, aLE = 0, aLE2 = 0;

    for (int ch = 0; ch < chunks; ++ch) {
        int r0 = rBase + ch * 16;
        __syncthreads();
        for (int idx = tid; idx < 2304; idx += 1024) {
            int rl = idx >> 7, q4 = (idx & 127) << 2;
            int gy = r0 - 1 + rl;
            float4 y4 = {0.f, 0.f, 0.f, 0.f};
            float4 e4 = {0.f, 0.f, 0.f, 0.f};
            if (gy >= 0 && gy < W512) {
                size_t o = (size_t)gy * W512 + q4;
                float4 R = *reinterpret_cast<const float4*>(Rp + o);
                float4 G = *reinterpret_cast<const float4*>(Gp + o);
                float4 B = *reinterpret_cast<const float4*>(Bp + o);
                float4 P = *reinterpret_cast<const float4*>(Pp + o);
                float4 N = *reinterpret_cast<const float4*>(Np + o);
                y4.x = fminf(fmaxf(0.299f * R.x + 0.587f * G.x + 0.114f * B.x, 0.f), 1.f);
                y4.y = fminf(fmaxf(0.299f * R.y + 0.587f * G.y + 0.114f * B.y, 0.f), 1.f);
                y4.z = fminf(fmaxf(0.299f * R.z + 0.587f * G.z + 0.114f * B.z, 0.f), 1.f);
                y4.w = fminf(fmaxf(0.299f * R.w + 0.587f * G.w + 0.114f * B.w, 0.f), 1.f);
                e4.x = fmaxf((P.x + N.x) * (1.f / 255.f), 0.f);
                e4.y = fmaxf((P.y + N.y) * (1.f / 255.f), 0.f);
                e4.z = fmaxf((P.z + N.z) * (1.f / 255.f), 0.f);
                e4.w = fmaxf((P.w + N.w) * (1.f / 255.f), 0.f);
                if (rl >= 1 && rl <= 16) {
                    float pnx = P.x * (1.f / 255.f), nnx = N.x * (1.f / 255.f);
                    float pny = P.y * (1.f / 255.f), nny = N.y * (1.f / 255.f);
                    float pnz = P.z * (1.f / 255.f), nnz = N.z * (1.f / 255.f);
                    float pnw = P.w * (1.f / 255.f), nnw = N.w * (1.f / 255.f);
                    aPb += (pnx - nnx) * __builtin_amdgcn_rcpf(pnx + nnx + 1e-12f);
                    aPb += (pny - nny) * __builtin_amdgcn_rcpf(pny + nny + 1e-12f);
                    aPb += (pnz - nnz) * __builtin_amdgcn_rcpf(pnz + nnz + 1e-12f);
                    aPb += (pnw - nnw) * __builtin_amdgcn_rcpf(pnw + nnw + 1e-12f);
                }
            }
            uint2 py, pe;
            py.x = pk_bf16(y4.x, y4.y); py.y = pk_bf16(y4.z, y4.w);
            pe.x = pk_bf16(e4.x, e4.y); pe.y = pk_bf16(e4.z, e4.w);
            *reinterpret_cast<uint2*>(&sYb[rl][8 + q4]) = py;
            *reinterpret_cast<uint2*>(&sEb[rl][8 + q4]) = pe;
        }
        __syncthreads();

        float ce = 0.f;
        #pragma unroll
        for (int q = 0; q < 2; ++q) {
            int qi = tid + (q << 10);
            int row = qi >> 7, c4 = (qi & 127) << 2;
            int lr = row + 1, base = 8 + c4;
            float y0[6], y1[6], y2[6], er[6];
            row6(&sYb[lr - 1][0], base, y0);
            row6(&sYb[lr][0],     base, y1);
            row6(&sYb[lr + 1][0], base, y2);
            row6(&sEb[lr][0],     base, er);
            uint2 U = *reinterpret_cast<const uint2*>(&sEb[lr - 1][base]);
            uint2 D = *reinterpret_cast<const uint2*>(&sEb[lr + 1][base]);
            float eu[4] = {lo16(U.x), hi16(U.x), lo16(U.y), hi16(U.y)};
            float ed[4] = {lo16(D.x), hi16(D.x), lo16(D.y), hi16(D.y)};
            #pragma unroll
            for (int j = 0; j < 4; ++j) {
                float y = y1[j + 1];
                float lap = y0[j + 1] + y2[j + 1] + y1[j] + y1[j + 2] - 4.f * y;
                float gx  = (y0[j + 2] + 2.f * y1[j + 2] + y2[j + 2])
                          - (y0[j]     + 2.f * y1[j]     + y2[j]);
                float gy2 = (y2[j] + 2.f * y2[j + 1] + y2[j + 2])
                          - (y0[j] + 2.f * y0[j + 1] + y0[j + 2]);
                float gm = sqrtf(gx * gx + gy2 * gy2);
                float e = er[j + 1];
                float lapE = eu[j] + ed[j] + er[j] + er[j + 2] - 4.f * e;
                aY += y; aY2 += y * y; aL += lap; aL2 += lap * lap; aG += gm;
                aLE += lapE; aLE2 += lapE * lapE; ce += e;
            }
        }
        cellPart[tid] = ce;
        __syncthreads();
        if (tid < 16) {
            float s = 0.f;
            for (int rg = 0; rg < 8; ++rg)
                for (int k = 0; k < 8; ++k)
                    s += cellPart[rg * 128 + tid * 8 + k];
            if (nb == 1) cellFull[(r0 >> 5) * 16 + tid] += s;
            else         partials[(size_t)blk * 32 + 9 + tid] = s;
        }
    }
    __syncthreads();

    float v[8] = {aY, aY2, aL, aL2, aG, aPb, aLE, aLE2};
    #pragma unroll
    for (int off = 32; off; off >>= 1)
        #pragma unroll
        for (int k = 0; k < 8; ++k) v[k] += __shfl_down(v[k], off);
    int lane = tid & 63, wid = tid >> 6;
    if (lane == 0)
        for (int k = 0; k < 8; ++k) red[wid][k] = v[k];
    __syncthreads();

    if (tid == 0) {
        float s[8];
        for (int k = 0; k < 8; ++k) {
            float t = 0.f;
            for (int w = 0; w < 16; ++w) t += red[w][k];
            s[k] = t;
        }
        if (nb > 1) {
            float* rec = partials + (size_t)blk * 32;
            for (int k = 0; k < 8; ++k) rec[k] = s[k];
        } else {
            float c1 = 0.f, c2 = 0.f, ct = 0.f;
            for (int j = 0; j < 256; ++j) {
                float m = cellFull[j] * (1.f / 1024.f);
                c1 += m; c2 += m * m; ct += cellFull[j];
            }
            const float FN = 262144.f;
            float muY   = s[0] / FN;
            float stdY  = sqrtf(fmaxf(s[1] / FN - muY * muY, 0.f));
            float varlp = fmaxf(s[3] - s[2] * s[2] / FN, 0.f) / (FN - 1.f);
            float gmean = s[4] / FN;
            float mc = c1 * (1.f / 256.f);
            float vc = fmaxf(c2 * (1.f / 256.f) - mc * mc, 0.f);
            float cv = sqrtf(vc) / (mc + 1e-12f);
            float dens = ct / FN;
            float pb = s[5] / FN;
            float varlpE = fmaxf(s[7] - s[6] * s[6] / FN, 0.f) / (FN - 1.f);
            float* zb = z + b * 8;
            zb[0] = muY; zb[1] = stdY; zb[2] = varlp; zb[3] = gmean;
            zb[4] = cv;  zb[5] = dens; zb[6] = pb;    zb[7] = varlpE;
        }
    }
}

// ---------------------------------------------------------------------------
// k_finalize (fast path): merge 32 band records per batch -> z[16][8]
// ---------------------------------------------------------------------------
__global__ __launch_bounds__(256) void k_finalize(
    const float* __restrict__ partials, float* __restrict__ z)
{
    __shared__ float sred[8];
    __shared__ float rr[4][3];
    int b = blockIdx.x, tid = threadIdx.x;
    if (tid < 8) {
        float s = 0.f;
        for (int band = 0; band < 32; ++band)
            s += partials[(size_t)(b * 32 + band) * 32 + tid];
        sred[tid] = s;
    }
    int cr = tid >> 4, cc = tid & 15;
    float cell = partials[(size_t)(b * 32 + 2 * cr)     * 32 + 9 + cc]
               + partials[(size_t)(b * 32 + 2 * cr + 1) * 32 + 9 + cc];
    float m = cell * (1.f / 1024.f);
    float c1 = m, c2 = m * m, ct = cell;
    #pragma unroll
    for (int off = 32; off; off >>= 1) {
        c1 += __shfl_down(c1, off);
        c2 += __shfl_down(c2, off);
        ct += __shfl_down(ct, off);
    }
    int lane = tid & 63, wid = tid >> 6;
    if (lane == 0) { rr[wid][0] = c1; rr[wid][1] = c2; rr[wid][2] = ct; }
    __syncthreads();
    if (tid == 0) {
        float C1 = rr[0][0] + rr[1][0] + rr[2][0] + rr[3][0];
        float C2 = rr[0][1] + rr[1][1] + rr[2][1] + rr[3][1];
        float CT = rr[0][2] + rr[1][2] + rr[2][2] + rr[3][2];
        const float FN = 262144.f;
        float muY   = sred[0] / FN;
        float stdY  = sqrtf(fmaxf(sred[1] / FN - muY * muY, 0.f));
        float varlp = fmaxf(sred[3] - sred[2] * sred[2] / FN, 0.f) / (FN - 1.f);
        float gmean = sred[4] / FN;
        float mc = C1 * (1.f / 256.f);
        float vc = fmaxf(C2 * (1.f / 256.f) - mc * mc, 0.f);
        float cv = sqrtf(vc) / (mc + 1e-12f);
        float dens = CT / FN;
        float pb = sred[5] / FN;
        float varlpE = fmaxf(sred[7] - sred[6] * sred[6] / FN, 0.f) / (FN - 1.f);
        float* zb = z + b * 8;
        zb[0] = muY; zb[1] = stdY; zb[2] = varlp; zb[3] = gmean;
        zb[4] = cv;  zb[5] = dens; zb[6] = pb;    zb[7] = varlpE;
    }
}

// ---------------------------------------------------------------------------
// k_mlp: metrics MLP -> coefs  +  build bf16 MFMA weight fragments in ws.
// ---------------------------------------------------------------------------
__global__ __launch_bounds__(1024) void k_mlp(
    const float* __restrict__ z,
    const float* __restrict__ w1, const float* __restrict__ b1,
    const float* __restrict__ w2, const float* __restrict__ b2,
    const float* __restrict__ hgw, const float* __restrict__ hgb,
    const float* __restrict__ hfw, const float* __restrict__ hfb,
    const float* __restrict__ rs,
    const float* __restrict__ c1w,
    const float* __restrict__ bn1g, const float* __restrict__ bn1b,
    const float* __restrict__ bn1m, const float* __restrict__ bn1v,
    const float* __restrict__ c2w,
    const float* __restrict__ bn2g, const float* __restrict__ bn2b,
    const float* __restrict__ bn2m, const float* __restrict__ bn2v,
    float* __restrict__ coefA, float* __restrict__ cBp,
    u16* __restrict__ w1frag, u16* __restrict__ w2frag,
    float* __restrict__ b1f)
{
    int j = threadIdx.x, b = threadIdx.y;
    int ft = b * 64 + j;   // flat 0..1023

    for (int t = ft; t < 1536; t += 1024) {          // w1frag[m][lane][8]
        int m = t >> 9, ln = (t >> 3) & 63, sl = t & 7;
        int oc = ln & 15, gg = ln >> 4;
        int tap = m * 4 + gg;
        float v = 0.f;
        if (tap < 9 && sl < 5)
            v = c1w[oc * 45 + sl * 9 + tap] * (bn1g[oc] * rsqrtf(bn1v[oc] + 1e-5f));
        w1frag[t] = (u16)f2b_rtne(v);
    }
    for (int t = ft; t < 2560; t += 1024) {          // w2frag[m][lane][8]
        int m = t >> 9, ln = (t >> 3) & 63, sl = t & 7;
        int oc = ln & 15, gg = ln >> 4;
        int tap = 2 * m + (gg >> 1);
        int ic = (gg & 1) * 8 + sl;
        float v = 0.f;
        if (oc < 5 && tap < 9)
            v = c2w[oc * 144 + ic * 9 + tap] * (bn2g[oc] * rsqrtf(bn2v[oc] + 1e-5f));
        w2frag[t] = (u16)f2b_rtne(v);
    }
    if (ft < 16) {
        float inv = bn1g[ft] * rsqrtf(bn1v[ft] + 1e-5f);
        b1f[ft] = bn1b[ft] - bn1m[ft] * inv;
    }

    __shared__ float sZ[16][8], sH1[16][64], sH2[16][64], sG[16][2], sF[16][10];
    if (j < 8) sZ[b][j] = z[b * 8 + j];
    __syncthreads();
    float a = b1[j];
    #pragma unroll
    for (int k = 0; k < 8; ++k) a += sZ[b][k] * w1[j * 8 + k];
    sH1[b][j] = fmaxf(a, 0.f);
    __syncthreads();
    float a2 = b2[j];
    for (int k = 0; k < 64; ++k) a2 += sH1[b][k] * w2[j * 64 + k];
    sH2[b][j] = fmaxf(a2, 0.f);
    __syncthreads();
    if (j < 2) {
        float g = hgb[j];
        for (int k = 0; k < 64; ++k) g += sH2[b][k] * hgw[j * 64 + k];
        sG[b][j] = 1.f / (1.f + __expf(-g));
    }
    if (j < 10) {
        float f = hfb[j];
        for (int k = 0; k < 64; ++k) f += sH2[b][k] * hfw[j * 64 + k];
        sF[b][j] = f;
    }
    __syncthreads();
    if (j < 5) {
        float gs = sG[b][0] + sG[b][1] + 1e-12f;
        float alpha = (j < 2 ? sG[b][0] : sG[b][1]) / gs;
        float gamma = 1.f + 0.1f * sF[b][j];
        float beta  = 0.1f * sF[b][5 + j];
        float r = rs[0];
        float inv2 = bn2g[j] * rsqrtf(bn2v[j] + 1e-5f);
        float b2fold = bn2b[j] - bn2m[j] * inv2;
        float cA = r * alpha * gamma;
        coefA[b * 5 + j] = cA;
        cBp[b * 5 + j]   = r * alpha * beta + cA * b2fold;  // conv2 bias folded
    }
}

// ---------------------------------------------------------------------------
// k_main (MFMA): conv1+bn1+silu+conv2+bn2 + FiLM + residual.
// grid (16,32,16) = 32x16 tiles, 256 threads (4 waves), 3 blocks/CU.
// v13: N-tiles processed in independent PAIRS per wave — breaks the serial
// MFMA accumulator chains (interleaved accA/accB) and lets tile-B LDS reads
// issue under tile-A compute.
// ---------------------------------------------------------------------------
__global__ __launch_bounds__(256, 3) void k_main(
    const float* __restrict__ ev, const float* __restrict__ fr,
    const u16* __restrict__ w1frag, const u16* __restrict__ w2frag,
    const float* __restrict__ b1f,
    const float* __restrict__ coefA, const float* __restrict__ cBp,
    float* __restrict__ out)
{
    __shared__ __align__(16) u16 sIn[20 * 40 * 8];    // 12800 B
    __shared__ __align__(16) u16 sT1[18 * 34 * 24];   // 29376 B

    int tid = threadIdx.x;
    int lane = tid & 63, wv = tid >> 6;
    int g = lane >> 4, col = lane & 15;
    int b = blockIdx.z;
    int ty0 = blockIdx.y * 16, tx0 = blockIdx.x * 32;

    const float* p0 = ev + (size_t)(b * 2)     * HW;
    const float* p1 = ev + (size_t)(b * 2 + 1) * HW;
    const float* p2 = fr + (size_t)(b * 3)     * HW;
    const float* p3 = fr + (size_t)(b * 3 + 1) * HW;
    const float* p4 = fr + (size_t)(b * 3 + 2) * HW;

    // ---- stage sIn: 200 groups of 4 aligned px, channel-minor bf16 ----
    if (tid < 200) {
        int r = tid / 10, k = tid % 10;
        int gy = ty0 - 2 + r, gx = tx0 - 4 + 4 * k;
        float4 v0 = {0,0,0,0}, v1 = {0,0,0,0}, v2 = {0,0,0,0}, v3 = {0,0,0,0}, v4 = {0,0,0,0};
        if (gy >= 0 && gy < W512 && gx >= 0 && gx < W512) {
            size_t o = (size_t)gy * W512 + gx;
            v0 = *reinterpret_cast<const float4*>(p0 + o);
            v1 = *reinterpret_cast<const float4*>(p1 + o);
            v2 = *reinterpret_cast<const float4*>(p2 + o);
            v3 = *reinterpret_cast<const float4*>(p3 + o);
            v4 = *reinterpret_cast<const float4*>(p4 + o);
        }
        int base = (r * 40 + 4 * k) * 8;
        const float* a0 = (const float*)&v0;
        const float* a1 = (const float*)&v1;
        const float* a2 = (const float*)&v2;
        const float* a3 = (const float*)&v3;
        const float* a4 = (const float*)&v4;
        #pragma unroll
        for (int jx = 0; jx < 4; ++jx) {
            uint4 pk;
            pk.x = pk_bf16(a0[jx], a1[jx]);
            pk.y = pk_bf16(a2[jx], a3[jx]);
            pk.z = pk_bf16(a4[jx], 0.f);
            pk.w = 0;
            *reinterpret_cast<uint4*>(&sIn[base + jx * 8]) = pk;
        }
    }

    // ---- A fragments + per-lane B byte-offsets ----
    short8 a1f[3], a2f[5];
    #pragma unroll
    for (int m = 0; m < 3; ++m)
        a1f[m] = *reinterpret_cast<const short8*>(&w1frag[(m * 64 + lane) * 8]);
    #pragma unroll
    for (int m = 0; m < 5; ++m)
        a2f[m] = *reinterpret_cast<const short8*>(&w2frag[(m * 64 + lane) * 8]);
    f32x4 b1v = *reinterpret_cast<const f32x4*>(&b1f[g * 4]);

    int boff1[3];
    #pragma unroll
    for (int m = 0; m < 3; ++m) {
        int tap = m * 4 + g; if (tap > 8) tap = 8;
        boff1[m] = ((tap / 3) * 40 + (tap % 3)) * 16;
    }
    int boff2[5];
    #pragma unroll
    for (int m = 0; m < 5; ++m) {
        int tap = 2 * m + (g >> 1); if (tap > 8) tap = 8;
        boff2[m] = ((tap / 3) * 34 + (tap % 3)) * 48 + (g & 1) * 16;
    }

    __syncthreads();

    // ---- conv1: 39 N-tiles over 18x34 domain, processed in pairs ----
    for (int t = wv; t < 39; t += 8) {
        bool hasB = (t + 4 < 39);
        int qA = t * 16 + col;
        int qB = hasB ? (qA + 64) : qA;
        int qcA = qA > 611 ? 611 : qA;
        int qcB = qB > 611 ? 611 : qB;
        int rA = qcA / 34, cA = qcA - rA * 34;
        int rB = qcB / 34, cB = qcB - rB * 34;
        const char* baseA = (const char*)&sIn[(rA * 40 + cA + 2) * 8];
        const char* baseB = (const char*)&sIn[(rB * 40 + cB + 2) * 8];
        short8 fA0 = *reinterpret_cast<const short8*>(baseA + boff1[0]);
        short8 fB0 = *reinterpret_cast<const short8*>(baseB + boff1[0]);
        short8 fA1 = *reinterpret_cast<const short8*>(baseA + boff1[1]);
        short8 fB1 = *reinterpret_cast<const short8*>(baseB + boff1[1]);
        short8 fA2 = *reinterpret_cast<const short8*>(baseA + boff1[2]);
        short8 fB2 = *reinterpret_cast<const short8*>(baseB + boff1[2]);
        f32x4 accA = {0.f, 0.f, 0.f, 0.f};
        f32x4 accB = {0.f, 0.f, 0.f, 0.f};
        accA = __builtin_amdgcn_mfma_f32_16x16x32_bf16(a1f[0], fA0, accA, 0, 0, 0);
        accB = __builtin_amdgcn_mfma_f32_16x16x32_bf16(a1f[0], fB0, accB, 0, 0, 0);
        accA = __builtin_amdgcn_mfma_f32_16x16x32_bf16(a1f[1], fA1, accA, 0, 0, 0);
        accB = __builtin_amdgcn_mfma_f32_16x16x32_bf16(a1f[1], fB1, accB, 0, 0, 0);
        accA = __builtin_amdgcn_mfma_f32_16x16x32_bf16(a1f[2], fA2, accA, 0, 0, 0);
        accB = __builtin_amdgcn_mfma_f32_16x16x32_bf16(a1f[2], fB2, accB, 0, 0, 0);

        {   // tile A epilogue
            int gy1 = ty0 - 1 + rA, gx1 = tx0 - 1 + cA;
            bool inimg = (gy1 >= 0 && gy1 < W512 && gx1 >= 0 && gx1 < W512);
            float v0 = silu_fast(accA[0] + b1v[0]);
            float v1 = silu_fast(accA[1] + b1v[1]);
            float v2 = silu_fast(accA[2] + b1v[2]);
            float v3 = silu_fast(accA[3] + b1v[3]);
            if (!inimg) { v0 = v1 = v2 = v3 = 0.f; }
            uint2 pk;
            pk.x = pk_bf16(v0, v1);
            pk.y = pk_bf16(v2, v3);
            *reinterpret_cast<uint2*>(&sT1[(rA * 34 + cA) * 24 + g * 4]) = pk;
        }
        if (hasB) {   // tile B epilogue
            int gy1 = ty0 - 1 + rB, gx1 = tx0 - 1 + cB;
            bool inimg = (gy1 >= 0 && gy1 < W512 && gx1 >= 0 && gx1 < W512);
            float v0 = silu_fast(accB[0] + b1v[0]);
            float v1 = silu_fast(accB[1] + b1v[1]);
            float v2 = silu_fast(accB[2] + b1v[2]);
            float v3 = silu_fast(accB[3] + b1v[3]);
            if (!inimg) { v0 = v1 = v2 = v3 = 0.f; }
            uint2 pk;
            pk.x = pk_bf16(v0, v1);
            pk.y = pk_bf16(v2, v3);
            *reinterpret_cast<uint2*>(&sT1[(rB * 34 + cB) * 24 + g * 4]) = pk;
        }
    }
    __syncthreads();

    // ---- conv2 + epilogue: 32 N-tiles over 32x16, processed in pairs ----
    float cA0 = coefA[b * 5 + 0], cA1 = coefA[b * 5 + 1], cA2 = coefA[b * 5 + 2];
    float cA3 = coefA[b * 5 + 3], cA4 = coefA[b * 5 + 4];
    float cB0 = cBp[b * 5 + 0], cB1 = cBp[b * 5 + 1], cB2 = cBp[b * 5 + 2];
    float cB3 = cBp[b * 5 + 3], cB4 = cBp[b * 5 + 4];
    const size_t OUT2 = (size_t)32 * HW;

    for (int t = wv; t < 32; t += 8) {
        int qA = t * 16 + col;
        int qB = qA + 64;
        int rA = qA >> 5, cA = qA & 31;
        int rB = qB >> 5, cB = qB & 31;
        const char* baseA = (const char*)&sT1[(rA * 34 + cA) * 24];
        const char* baseB = (const char*)&sT1[(rB * 34 + cB) * 24];
        f32x4 accA = {0.f, 0.f, 0.f, 0.f};
        f32x4 accB = {0.f, 0.f, 0.f, 0.f};
        #pragma unroll
        for (int m = 0; m < 5; ++m) {
            short8 fA = *reinterpret_cast<const short8*>(baseA + boff2[m]);
            short8 fB = *reinterpret_cast<const short8*>(baseB + boff2[m]);
            accA = __builtin_amdgcn_mfma_f32_16x16x32_bf16(a2f[m], fA, accA, 0, 0, 0);
            accB = __builtin_amdgcn_mfma_f32_16x16x32_bf16(a2f[m], fB, accB, 0, 0, 0);
        }
        size_t pxA = (size_t)(ty0 + rA) * W512 + (tx0 + cA);
        size_t pxB = (size_t)(ty0 + rB) * W512 + (tx0 + cB);
        if (g == 0) {   // oc 0..3
            out[(size_t)(b * 2 + 0) * HW + pxA] = p0[pxA] + cA0 * accA[0] + cB0;
            out[(size_t)(b * 2 + 0) * HW + pxB] = p0[pxB] + cA0 * accB[0] + cB0;
            out[(size_t)(b * 2 + 1) * HW + pxA] = p1[pxA] + cA1 * accA[1] + cB1;
            out[(size_t)(b * 2 + 1) * HW + pxB] = p1[pxB] + cA1 * accB[1] + cB1;
            out[OUT2 + (size_t)(b * 3 + 0) * HW + pxA] = p2[pxA] + cA2 * accA[2] + cB2;
            out[OUT2 + (size_t)(b * 3 + 0) * HW + pxB] = p2[pxB] + cA2 * accB[2] + cB2;
            out[OUT2 + (size_t)(b * 3 + 1) * HW + pxA] = p3[pxA] + cA3 * accA[3] + cB3;
            out[OUT2 + (size_t)(b * 3 + 1) * HW + pxB] = p3[pxB] + cA3 * accB[3] + cB3;
        } else if (g == 1) {   // oc 4
            out[OUT2 + (size_t)(b * 3 + 2) * HW + pxA] = p4[pxA] + cA4 * accA[0] + cB4;
            out[OUT2 + (size_t)(b * 3 + 2) * HW + pxB] = p4[pxB] + cA4 * accB[0] + cB4;
        }
    }
}

// ---------------------------------------------------------------------------
extern "C" void kernel_launch(void* const* d_in, const int* in_sizes, int n_in,
                              void* d_out, int out_size, void* d_ws, size_t ws_size,
                              hipStream_t stream)
{
    const float* ev = (const float*)d_in[0];
    const float* fr = (const float*)d_in[1];

    char* wb = (char*)d_ws;
    float* coefA    = (float*)(wb + 0);      // 80 f
    float* cBp      = (float*)(wb + 320);    // 80 f
    float* b1f      = (float*)(wb + 640);    // 16 f
    u16*   w1frag   = (u16*) (wb + 768);     // 1536 u16
    u16*   w2frag   = (u16*) (wb + 3840);    // 2560 u16
    float* zbuf     = (float*)(wb + 8960);   // 128 f
    float* partials = (float*)(wb + 10240);  // 16384 f  -> total 75776 B

    bool fast = (ws_size >= 75776);
    int nb   = fast ? 32 : 1;
    int nblk = fast ? 512 : 16;
    k_band<<<dim3(nblk), dim3(1024), 0, stream>>>(ev, fr, nb, partials, zbuf);
    if (fast) k_finalize<<<dim3(16), dim3(256), 0, stream>>>(partials, zbuf);

    k_mlp<<<dim3(1), dim3(64, 16), 0, stream>>>(zbuf,
        (const float*)d_in[12], (const float*)d_in[13], (const float*)d_in[14], (const float*)d_in[15],
        (const float*)d_in[16], (const float*)d_in[17], (const float*)d_in[18], (const float*)d_in[19],
        (const float*)d_in[20],
        (const float*)d_in[2], (const float*)d_in[3], (const float*)d_in[4], (const float*)d_in[5],
        (const float*)d_in[6], (const float*)d_in[7], (const float*)d_in[8], (const float*)d_in[9],
        (const float*)d_in[10], (const float*)d_in[11],
        coefA, cBp, w1frag, w2frag, b1f);

    k_main<<<dim3(16, 32, 16), dim3(256), 0, stream>>>(ev, fr,
        w1frag, w2frag, b1f, coefA, cBp, (float*)d_out);
}

// Round 14
// 128.798 us; speedup vs baseline: 2.8875x; 1.0926x over previous
//
#include <hip/hip_runtime.h>
#include <hip/hip_bf16.h>

typedef unsigned int   u32;
typedef unsigned short u16;

#define HW 262144   // 512*512
#define W512 512

typedef __attribute__((ext_vector_type(8))) short short8;   // 8 bf16 (4 VGPRs)
typedef __attribute__((ext_vector_type(4))) float f32x4;

__device__ __forceinline__ u32 f2b_rtne(float f) {   // f32 -> bf16 bits (RTNE)
    union { float f; u32 i; } c; c.f = f;
    u32 u = c.i;
    return (u + 0x7FFFu + ((u >> 16) & 1u)) >> 16;
}
__device__ __forceinline__ u32 pk_bf16(float lo, float hi) {  // 2xf32 -> packed bf16 pair
    float2 t; t.x = lo; t.y = hi;
    __hip_bfloat162 h = __float22bfloat162_rn(t);
    return *reinterpret_cast<u32*>(&h);
}
__device__ __forceinline__ float lo16(u32 w) {
    union { u32 i; float f; } c; c.i = w << 16; return c.f;
}
__device__ __forceinline__ float hi16(u32 w) {
    union { u32 i; float f; } c; c.i = w & 0xFFFF0000u; return c.f;
}
__device__ __forceinline__ float silu_fast(float v) {
    return v * __builtin_amdgcn_rcpf(1.f + __expf(-v));
}

// load 6 consecutive bf16 values [c4-1 .. c4+4] from a padded row (base = 8+c4)
__device__ __forceinline__ void row6(const u16* rowp, int base, float* o) {
    uint2 A = *reinterpret_cast<const uint2*>(rowp + base - 4);
    uint2 B = *reinterpret_cast<const uint2*>(rowp + base);
    uint2 C = *reinterpret_cast<const uint2*>(rowp + base + 4);
    o[0] = hi16(A.y);
    o[1] = lo16(B.x); o[2] = hi16(B.x);
    o[3] = lo16(B.y); o[4] = hi16(B.y);
    o[5] = lo16(C.x);
}

// ---------------------------------------------------------------------------
// k_band: metrics over a horizontal band. nb bands/batch (32 fast, 1 slow).
// ---------------------------------------------------------------------------
__global__ __launch_bounds__(1024) void k_band(
    const float* __restrict__ ev, const float* __restrict__ fr,
    int nb, float* __restrict__ partials, float* __restrict__ z)
{
    __shared__ u16 sYb[18][528];   // bf16, data at cols 8..519
    __shared__ u16 sEb[18][528];
    __shared__ float cellPart[1024];
    __shared__ float cellFull[256];
    __shared__ float red[16][8];

    int blk = blockIdx.x;
    int b = blk / nb, band = blk % nb;
    int rowsPerBand = 512 / nb;
    int chunks = rowsPerBand >> 4;
    int rBase = band * rowsPerBand;
    int tid = threadIdx.x;

    const float* Pp = ev + (size_t)(b * 2)     * HW;
    const float* Np = ev + (size_t)(b * 2 + 1) * HW;
    const float* Rp = fr + (size_t)(b * 3)     * HW;
    const float* Gp = fr + (size_t)(b * 3 + 1) * HW;
    const float* Bp = fr + (size_t)(b * 3 + 2) * HW;

    if (nb == 1 && tid < 256) cellFull[tid] = 0.f;
    if (tid < 36) {
        int rr = tid >> 1, side = tid & 1;
        uint4 zz = {0, 0, 0, 0};
        *reinterpret_cast<uint4*>(&sYb[rr][side ? 520 : 0]) = zz;
        *reinterpret_cast<uint4*>(&sEb[rr][side ? 520 : 0]) = zz;
    }

    float aY = 0, aY2 = 0, aL = 0, aL2 = 0, aG = 0, aPb = 0, aLE = 0, aLE2 = 0;

    for (int ch = 0; ch < chunks; ++ch) {
        int r0 = rBase + ch * 16;
        __syncthreads();
        for (int idx = tid; idx < 2304; idx += 1024) {
            int rl = idx >> 7, q4 = (idx & 127) << 2;
            int gy = r0 - 1 + rl;
            float4 y4 = {0.f, 0.f, 0.f, 0.f};
            float4 e4 = {0.f, 0.f, 0.f, 0.f};
            if (gy >= 0 && gy < W512) {
                size_t o = (size_t)gy * W512 + q4;
                float4 R = *reinterpret_cast<const float4*>(Rp + o);
                float4 G = *reinterpret_cast<const float4*>(Gp + o);
                float4 B = *reinterpret_cast<const float4*>(Bp + o);
                float4 P = *reinterpret_cast<const float4*>(Pp + o);
                float4 N = *reinterpret_cast<const float4*>(Np + o);
                y4.x = fminf(fmaxf(0.299f * R.x + 0.587f * G.x + 0.114f * B.x, 0.f), 1.f);
                y4.y = fminf(fmaxf(0.299f * R.y + 0.587f * G.y + 0.114f * B.y, 0.f), 1.f);
                y4.z = fminf(fmaxf(0.299f * R.z + 0.587f * G.z + 0.114f * B.z, 0.f), 1.f);
                y4.w = fminf(fmaxf(0.299f * R.w + 0.587f * G.w + 0.114f * B.w, 0.f), 1.f);
                e4.x = fmaxf((P.x + N.x) * (1.f / 255.f), 0.f);
                e4.y = fmaxf((P.y + N.y) * (1.f / 255.f), 0.f);
                e4.z = fmaxf((P.z + N.z) * (1.f / 255.f), 0.f);
                e4.w = fmaxf((P.w + N.w) * (1.f / 255.f), 0.f);
                if (rl >= 1 && rl <= 16) {
                    float pnx = P.x * (1.f / 255.f), nnx = N.x * (1.f / 255.f);
                    float pny = P.y * (1.f / 255.f), nny = N.y * (1.f / 255.f);
                    float pnz = P.z * (1.f / 255.f), nnz = N.z * (1.f / 255.f);
                    float pnw = P.w * (1.f / 255.f), nnw = N.w * (1.f / 255.f);
                    aPb += (pnx - nnx) * __builtin_amdgcn_rcpf(pnx + nnx + 1e-12f);
                    aPb += (pny - nny) * __builtin_amdgcn_rcpf(pny + nny + 1e-12f);
                    aPb += (pnz - nnz) * __builtin_amdgcn_rcpf(pnz + nnz + 1e-12f);
                    aPb += (pnw - nnw) * __builtin_amdgcn_rcpf(pnw + nnw + 1e-12f);
                }
            }
            uint2 py, pe;
            py.x = pk_bf16(y4.x, y4.y); py.y = pk_bf16(y4.z, y4.w);
            pe.x = pk_bf16(e4.x, e4.y); pe.y = pk_bf16(e4.z, e4.w);
            *reinterpret_cast<uint2*>(&sYb[rl][8 + q4]) = py;
            *reinterpret_cast<uint2*>(&sEb[rl][8 + q4]) = pe;
        }
        __syncthreads();

        float ce = 0.f;
        #pragma unroll
        for (int q = 0; q < 2; ++q) {
            int qi = tid + (q << 10);
            int row = qi >> 7, c4 = (qi & 127) << 2;
            int lr = row + 1, base = 8 + c4;
            float y0[6], y1[6], y2[6], er[6];
            row6(&sYb[lr - 1][0], base, y0);
            row6(&sYb[lr][0],     base, y1);
            row6(&sYb[lr + 1][0], base, y2);
            row6(&sEb[lr][0],     base, er);
            uint2 U = *reinterpret_cast<const uint2*>(&sEb[lr - 1][base]);
            uint2 D = *reinterpret_cast<const uint2*>(&sEb[lr + 1][base]);
            float eu[4] = {lo16(U.x), hi16(U.x), lo16(U.y), hi16(U.y)};
            float ed[4] = {lo16(D.x), hi16(D.x), lo16(D.y), hi16(D.y)};
            #pragma unroll
            for (int j = 0; j < 4; ++j) {
                float y = y1[j + 1];
                float lap = y0[j + 1] + y2[j + 1] + y1[j] + y1[j + 2] - 4.f * y;
                float gx  = (y0[j + 2] + 2.f * y1[j + 2] + y2[j + 2])
                          - (y0[j]     + 2.f * y1[j]     + y2[j]);
                float gy2 = (y2[j] + 2.f * y2[j + 1] + y2[j + 2])
                          - (y0[j] + 2.f * y0[j + 1] + y0[j + 2]);
                float gm = sqrtf(gx * gx + gy2 * gy2);
                float e = er[j + 1];
                float lapE = eu[j] + ed[j] + er[j] + er[j + 2] - 4.f * e;
                aY += y; aY2 += y * y; aL += lap; aL2 += lap * lap; aG += gm;
                aLE += lapE; aLE2 += lapE * lapE; ce += e;
            }
        }
        cellPart[tid] = ce;
        __syncthreads();
        if (tid < 16) {
            float s = 0.f;
            for (int rg = 0; rg < 8; ++rg)
                for (int k = 0; k < 8; ++k)
                    s += cellPart[rg * 128 + tid * 8 + k];
            if (nb == 1) cellFull[(r0 >> 5) * 16 + tid] += s;
            else         partials[(size_t)blk * 32 + 9 + tid] = s;
        }
    }
    __syncthreads();

    float v[8] = {aY, aY2, aL, aL2, aG, aPb, aLE, aLE2};
    #pragma unroll
    for (int off = 32; off; off >>= 1)
        #pragma unroll
        for (int k = 0; k < 8; ++k) v[k] += __shfl_down(v[k], off);
    int lane = tid & 63, wid = tid >> 6;
    if (lane == 0)
        for (int k = 0; k < 8; ++k) red[wid][k] = v[k];
    __syncthreads();

    if (tid == 0) {
        float s[8];
        for (int k = 0; k < 8; ++k) {
            float t = 0.f;
            for (int w = 0; w < 16; ++w) t += red[w][k];
            s[k] = t;
        }
        if (nb > 1) {
            float* rec = partials + (size_t)blk * 32;
            for (int k = 0; k < 8; ++k) rec[k] = s[k];
        } else {
            float c1 = 0.f, c2 = 0.f, ct = 0.f;
            for (int j = 0; j < 256; ++j) {
                float m = cellFull[j] * (1.f / 1024.f);
                c1 += m; c2 += m * m; ct += cellFull[j];
            }
            const float FN = 262144.f;
            float muY   = s[0] / FN;
            float stdY  = sqrtf(fmaxf(s[1] / FN - muY * muY, 0.f));
            float varlp = fmaxf(s[3] - s[2] * s[2] / FN, 0.f) / (FN - 1.f);
            float gmean = s[4] / FN;
            float mc = c1 * (1.f / 256.f);
            float vc = fmaxf(c2 * (1.f / 256.f) - mc * mc, 0.f);
            float cv = sqrtf(vc) / (mc + 1e-12f);
            float dens = ct / FN;
            float pb = s[5] / FN;
            float varlpE = fmaxf(s[7] - s[6] * s[6] / FN, 0.f) / (FN - 1.f);
            float* zb = z + b * 8;
            zb[0] = muY; zb[1] = stdY; zb[2] = varlp; zb[3] = gmean;
            zb[4] = cv;  zb[5] = dens; zb[6] = pb;    zb[7] = varlpE;
        }
    }
}

// ---------------------------------------------------------------------------
// k_finalize (fast path): merge 32 band records per batch -> z[16][8]
// ---------------------------------------------------------------------------
__global__ __launch_bounds__(256) void k_finalize(
    const float* __restrict__ partials, float* __restrict__ z)
{
    __shared__ float sred[8];
    __shared__ float rr[4][3];
    int b = blockIdx.x, tid = threadIdx.x;
    if (tid < 8) {
        float s = 0.f;
        for (int band = 0; band < 32; ++band)
            s += partials[(size_t)(b * 32 + band) * 32 + tid];
        sred[tid] = s;
    }
    int cr = tid >> 4, cc = tid & 15;
    float cell = partials[(size_t)(b * 32 + 2 * cr)     * 32 + 9 + cc]
               + partials[(size_t)(b * 32 + 2 * cr + 1) * 32 + 9 + cc];
    float m = cell * (1.f / 1024.f);
    float c1 = m, c2 = m * m, ct = cell;
    #pragma unroll
    for (int off = 32; off; off >>= 1) {
        c1 += __shfl_down(c1, off);
        c2 += __shfl_down(c2, off);
        ct += __shfl_down(ct, off);
    }
    int lane = tid & 63, wid = tid >> 6;
    if (lane == 0) { rr[wid][0] = c1; rr[wid][1] = c2; rr[wid][2] = ct; }
    __syncthreads();
    if (tid == 0) {
        float C1 = rr[0][0] + rr[1][0] + rr[2][0] + rr[3][0];
        float C2 = rr[0][1] + rr[1][1] + rr[2][1] + rr[3][1];
        float CT = rr[0][2] + rr[1][2] + rr[2][2] + rr[3][2];
        const float FN = 262144.f;
        float muY   = sred[0] / FN;
        float stdY  = sqrtf(fmaxf(sred[1] / FN - muY * muY, 0.f));
        float varlp = fmaxf(sred[3] - sred[2] * sred[2] / FN, 0.f) / (FN - 1.f);
        float gmean = sred[4] / FN;
        float mc = C1 * (1.f / 256.f);
        float vc = fmaxf(C2 * (1.f / 256.f) - mc * mc, 0.f);
        float cv = sqrtf(vc) / (mc + 1e-12f);
        float dens = CT / FN;
        float pb = sred[5] / FN;
        float varlpE = fmaxf(sred[7] - sred[6] * sred[6] / FN, 0.f) / (FN - 1.f);
        float* zb = z + b * 8;
        zb[0] = muY; zb[1] = stdY; zb[2] = varlp; zb[3] = gmean;
        zb[4] = cv;  zb[5] = dens; zb[6] = pb;    zb[7] = varlpE;
    }
}

// ---------------------------------------------------------------------------
// k_mlp: metrics MLP -> coefs  +  build bf16 MFMA weight fragments in ws.
// ---------------------------------------------------------------------------
__global__ __launch_bounds__(1024) void k_mlp(
    const float* __restrict__ z,
    const float* __restrict__ w1, const float* __restrict__ b1,
    const float* __restrict__ w2, const float* __restrict__ b2,
    const float* __restrict__ hgw, const float* __restrict__ hgb,
    const float* __restrict__ hfw, const float* __restrict__ hfb,
    const float* __restrict__ rs,
    const float* __restrict__ c1w,
    const float* __restrict__ bn1g, const float* __restrict__ bn1b,
    const float* __restrict__ bn1m, const float* __restrict__ bn1v,
    const float* __restrict__ c2w,
    const float* __restrict__ bn2g, const float* __restrict__ bn2b,
    const float* __restrict__ bn2m, const float* __restrict__ bn2v,
    float* __restrict__ coefA, float* __restrict__ cBp,
    u16* __restrict__ w1frag, u16* __restrict__ w2frag,
    float* __restrict__ b1f)
{
    int j = threadIdx.x, b = threadIdx.y;
    int ft = b * 64 + j;   // flat 0..1023

    for (int t = ft; t < 1536; t += 1024) {          // w1frag[m][lane][8]
        int m = t >> 9, ln = (t >> 3) & 63, sl = t & 7;
        int oc = ln & 15, gg = ln >> 4;
        int tap = m * 4 + gg;
        float v = 0.f;
        if (tap < 9 && sl < 5)
            v = c1w[oc * 45 + sl * 9 + tap] * (bn1g[oc] * rsqrtf(bn1v[oc] + 1e-5f));
        w1frag[t] = (u16)f2b_rtne(v);
    }
    for (int t = ft; t < 2560; t += 1024) {          // w2frag[m][lane][8]
        int m = t >> 9, ln = (t >> 3) & 63, sl = t & 7;
        int oc = ln & 15, gg = ln >> 4;
        int tap = 2 * m + (gg >> 1);
        int ic = (gg & 1) * 8 + sl;
        float v = 0.f;
        if (oc < 5 && tap < 9)
            v = c2w[oc * 144 + ic * 9 + tap] * (bn2g[oc] * rsqrtf(bn2v[oc] + 1e-5f));
        w2frag[t] = (u16)f2b_rtne(v);
    }
    if (ft < 16) {
        float inv = bn1g[ft] * rsqrtf(bn1v[ft] + 1e-5f);
        b1f[ft] = bn1b[ft] - bn1m[ft] * inv;
    }

    __shared__ float sZ[16][8], sH1[16][64], sH2[16][64], sG[16][2], sF[16][10];
    if (j < 8) sZ[b][j] = z[b * 8 + j];
    __syncthreads();
    float a = b1[j];
    #pragma unroll
    for (int k = 0; k < 8; ++k) a += sZ[b][k] * w1[j * 8 + k];
    sH1[b][j] = fmaxf(a, 0.f);
    __syncthreads();
    float a2 = b2[j];
    for (int k = 0; k < 64; ++k) a2 += sH1[b][k] * w2[j * 64 + k];
    sH2[b][j] = fmaxf(a2, 0.f);
    __syncthreads();
    if (j < 2) {
        float g = hgb[j];
        for (int k = 0; k < 64; ++k) g += sH2[b][k] * hgw[j * 64 + k];
        sG[b][j] = 1.f / (1.f + __expf(-g));
    }
    if (j < 10) {
        float f = hfb[j];
        for (int k = 0; k < 64; ++k) f += sH2[b][k] * hfw[j * 64 + k];
        sF[b][j] = f;
    }
    __syncthreads();
    if (j < 5) {
        float gs = sG[b][0] + sG[b][1] + 1e-12f;
        float alpha = (j < 2 ? sG[b][0] : sG[b][1]) / gs;
        float gamma = 1.f + 0.1f * sF[b][j];
        float beta  = 0.1f * sF[b][5 + j];
        float r = rs[0];
        float inv2 = bn2g[j] * rsqrtf(bn2v[j] + 1e-5f);
        float b2fold = bn2b[j] - bn2m[j] * inv2;
        float cA = r * alpha * gamma;
        coefA[b * 5 + j] = cA;
        cBp[b * 5 + j]   = r * alpha * beta + cA * b2fold;  // conv2 bias folded
    }
}

// ---------------------------------------------------------------------------
// k_main (MFMA): conv1+bn1+silu+conv2+bn2 + FiLM + residual.
// grid (16,32,16) = 32x16 tiles, 256 threads (4 waves).
// v14: sT1 packed to 32B/px (16 ic exactly) -> LDS 32.4 KB -> 4 blocks/CU;
// interior-block fast path skips all bounds checks (82% of blocks);
// conv1 accumulators init directly to bias.
// ---------------------------------------------------------------------------
__global__ __launch_bounds__(256, 4) void k_main(
    const float* __restrict__ ev, const float* __restrict__ fr,
    const u16* __restrict__ w1frag, const u16* __restrict__ w2frag,
    const float* __restrict__ b1f,
    const float* __restrict__ coefA, const float* __restrict__ cBp,
    float* __restrict__ out)
{
    __shared__ __align__(16) u16 sIn[20 * 40 * 8];    // 12800 B
    __shared__ __align__(16) u16 sT1[18 * 34 * 16];   // 19584 B

    int tid = threadIdx.x;
    int lane = tid & 63, wv = tid >> 6;
    int g = lane >> 4, col = lane & 15;
    int b = blockIdx.z;
    int ty0 = blockIdx.y * 16, tx0 = blockIdx.x * 32;
    bool interior = (blockIdx.x >= 1 && blockIdx.x <= 14 &&
                     blockIdx.y >= 1 && blockIdx.y <= 30);

    const float* p0 = ev + (size_t)(b * 2)     * HW;
    const float* p1 = ev + (size_t)(b * 2 + 1) * HW;
    const float* p2 = fr + (size_t)(b * 3)     * HW;
    const float* p3 = fr + (size_t)(b * 3 + 1) * HW;
    const float* p4 = fr + (size_t)(b * 3 + 2) * HW;

    // ---- stage sIn: 200 groups of 4 aligned px, channel-minor bf16 ----
    if (tid < 200) {
        int r = tid / 10, k = tid % 10;
        int gy = ty0 - 2 + r, gx = tx0 - 4 + 4 * k;
        float4 v0, v1, v2, v3, v4;
        if (interior) {
            size_t o = (size_t)gy * W512 + gx;
            v0 = *reinterpret_cast<const float4*>(p0 + o);
            v1 = *reinterpret_cast<const float4*>(p1 + o);
            v2 = *reinterpret_cast<const float4*>(p2 + o);
            v3 = *reinterpret_cast<const float4*>(p3 + o);
            v4 = *reinterpret_cast<const float4*>(p4 + o);
        } else {
            v0 = v1 = v2 = v3 = v4 = float4{0, 0, 0, 0};
            if (gy >= 0 && gy < W512 && gx >= 0 && gx < W512) {
                size_t o = (size_t)gy * W512 + gx;
                v0 = *reinterpret_cast<const float4*>(p0 + o);
                v1 = *reinterpret_cast<const float4*>(p1 + o);
                v2 = *reinterpret_cast<const float4*>(p2 + o);
                v3 = *reinterpret_cast<const float4*>(p3 + o);
                v4 = *reinterpret_cast<const float4*>(p4 + o);
            }
        }
        int base = (r * 40 + 4 * k) * 8;
        const float* a0 = (const float*)&v0;
        const float* a1 = (const float*)&v1;
        const float* a2 = (const float*)&v2;
        const float* a3 = (const float*)&v3;
        const float* a4 = (const float*)&v4;
        #pragma unroll
        for (int jx = 0; jx < 4; ++jx) {
            uint4 pk;
            pk.x = pk_bf16(a0[jx], a1[jx]);
            pk.y = pk_bf16(a2[jx], a3[jx]);
            pk.z = pk_bf16(a4[jx], 0.f);
            pk.w = 0;
            *reinterpret_cast<uint4*>(&sIn[base + jx * 8]) = pk;
        }
    }

    // ---- A fragments + per-lane B byte-offsets ----
    short8 a1f[3], a2f[5];
    #pragma unroll
    for (int m = 0; m < 3; ++m)
        a1f[m] = *reinterpret_cast<const short8*>(&w1frag[(m * 64 + lane) * 8]);
    #pragma unroll
    for (int m = 0; m < 5; ++m)
        a2f[m] = *reinterpret_cast<const short8*>(&w2frag[(m * 64 + lane) * 8]);
    f32x4 b1v = *reinterpret_cast<const f32x4*>(&b1f[g * 4]);

    int boff1[3];
    #pragma unroll
    for (int m = 0; m < 3; ++m) {
        int tap = m * 4 + g; if (tap > 8) tap = 8;
        boff1[m] = ((tap / 3) * 40 + (tap % 3)) * 16;
    }
    int boff2[5];
    #pragma unroll
    for (int m = 0; m < 5; ++m) {
        int tap = 2 * m + (g >> 1); if (tap > 8) tap = 8;
        boff2[m] = ((tap / 3) * 34 + (tap % 3)) * 32 + (g & 1) * 16;
    }

    __syncthreads();

    // ---- conv1: 39 N-tiles over 18x34 domain, processed in pairs ----
    for (int t = wv; t < 39; t += 8) {
        bool hasB = (t + 4 < 39);
        int qA = t * 16 + col;
        int qB = hasB ? (qA + 64) : qA;
        int qcA = qA > 611 ? 611 : qA;
        int qcB = qB > 611 ? 611 : qB;
        int rA = qcA / 34, cA = qcA - rA * 34;
        int rB = qcB / 34, cB = qcB - rB * 34;
        const char* baseA = (const char*)&sIn[(rA * 40 + cA + 2) * 8];
        const char* baseB = (const char*)&sIn[(rB * 40 + cB + 2) * 8];
        short8 fA0 = *reinterpret_cast<const short8*>(baseA + boff1[0]);
        short8 fB0 = *reinterpret_cast<const short8*>(baseB + boff1[0]);
        short8 fA1 = *reinterpret_cast<const short8*>(baseA + boff1[1]);
        short8 fB1 = *reinterpret_cast<const short8*>(baseB + boff1[1]);
        short8 fA2 = *reinterpret_cast<const short8*>(baseA + boff1[2]);
        short8 fB2 = *reinterpret_cast<const short8*>(baseB + boff1[2]);
        f32x4 accA = b1v;
        f32x4 accB = b1v;
        accA = __builtin_amdgcn_mfma_f32_16x16x32_bf16(a1f[0], fA0, accA, 0, 0, 0);
        accB = __builtin_amdgcn_mfma_f32_16x16x32_bf16(a1f[0], fB0, accB, 0, 0, 0);
        accA = __builtin_amdgcn_mfma_f32_16x16x32_bf16(a1f[1], fA1, accA, 0, 0, 0);
        accB = __builtin_amdgcn_mfma_f32_16x16x32_bf16(a1f[1], fB1, accB, 0, 0, 0);
        accA = __builtin_amdgcn_mfma_f32_16x16x32_bf16(a1f[2], fA2, accA, 0, 0, 0);
        accB = __builtin_amdgcn_mfma_f32_16x16x32_bf16(a1f[2], fB2, accB, 0, 0, 0);

        {   // tile A epilogue
            float v0 = silu_fast(accA[0]);
            float v1 = silu_fast(accA[1]);
            float v2 = silu_fast(accA[2]);
            float v3 = silu_fast(accA[3]);
            if (!interior) {
                int gy1 = ty0 - 1 + rA, gx1 = tx0 - 1 + cA;
                bool inimg = (gy1 >= 0 && gy1 < W512 && gx1 >= 0 && gx1 < W512);
                if (!inimg) { v0 = v1 = v2 = v3 = 0.f; }
            }
            uint2 pk;
            pk.x = pk_bf16(v0, v1);
            pk.y = pk_bf16(v2, v3);
            *reinterpret_cast<uint2*>(&sT1[(rA * 34 + cA) * 16 + g * 4]) = pk;
        }
        if (hasB) {   // tile B epilogue
            float v0 = silu_fast(accB[0]);
            float v1 = silu_fast(accB[1]);
            float v2 = silu_fast(accB[2]);
            float v3 = silu_fast(accB[3]);
            if (!interior) {
                int gy1 = ty0 - 1 + rB, gx1 = tx0 - 1 + cB;
                bool inimg = (gy1 >= 0 && gy1 < W512 && gx1 >= 0 && gx1 < W512);
                if (!inimg) { v0 = v1 = v2 = v3 = 0.f; }
            }
            uint2 pk;
            pk.x = pk_bf16(v0, v1);
            pk.y = pk_bf16(v2, v3);
            *reinterpret_cast<uint2*>(&sT1[(rB * 34 + cB) * 16 + g * 4]) = pk;
        }
    }
    __syncthreads();

    // ---- conv2 + epilogue: 32 N-tiles over 32x16, processed in pairs ----
    float cA0 = coefA[b * 5 + 0], cA1 = coefA[b * 5 + 1], cA2 = coefA[b * 5 + 2];
    float cA3 = coefA[b * 5 + 3], cA4 = coefA[b * 5 + 4];
    float cB0 = cBp[b * 5 + 0], cB1 = cBp[b * 5 + 1], cB2 = cBp[b * 5 + 2];
    float cB3 = cBp[b * 5 + 3], cB4 = cBp[b * 5 + 4];
    const size_t OUT2 = (size_t)32 * HW;

    for (int t = wv; t < 32; t += 8) {
        int qA = t * 16 + col;
        int qB = qA + 64;
        int rA = qA >> 5, cA = qA & 31;
        int rB = qB >> 5, cB = qB & 31;
        const char* baseA = (const char*)&sT1[(rA * 34 + cA) * 16];
        const char* baseB = (const char*)&sT1[(rB * 34 + cB) * 16];
        f32x4 accA = {0.f, 0.f, 0.f, 0.f};
        f32x4 accB = {0.f, 0.f, 0.f, 0.f};
        #pragma unroll
        for (int m = 0; m < 5; ++m) {
            short8 fA = *reinterpret_cast<const short8*>(baseA + boff2[m]);
            short8 fB = *reinterpret_cast<const short8*>(baseB + boff2[m]);
            accA = __builtin_amdgcn_mfma_f32_16x16x32_bf16(a2f[m], fA, accA, 0, 0, 0);
            accB = __builtin_amdgcn_mfma_f32_16x16x32_bf16(a2f[m], fB, accB, 0, 0, 0);
        }
        size_t pxA = (size_t)(ty0 + rA) * W512 + (tx0 + cA);
        size_t pxB = (size_t)(ty0 + rB) * W512 + (tx0 + cB);
        if (g == 0) {   // oc 0..3
            out[(size_t)(b * 2 + 0) * HW + pxA] = p0[pxA] + cA0 * accA[0] + cB0;
            out[(size_t)(b * 2 + 0) * HW + pxB] = p0[pxB] + cA0 * accB[0] + cB0;
            out[(size_t)(b * 2 + 1) * HW + pxA] = p1[pxA] + cA1 * accA[1] + cB1;
            out[(size_t)(b * 2 + 1) * HW + pxB] = p1[pxB] + cA1 * accB[1] + cB1;
            out[OUT2 + (size_t)(b * 3 + 0) * HW + pxA] = p2[pxA] + cA2 * accA[2] + cB2;
            out[OUT2 + (size_t)(b * 3 + 0) * HW + pxB] = p2[pxB] + cA2 * accB[2] + cB2;
            out[OUT2 + (size_t)(b * 3 + 1) * HW + pxA] = p3[pxA] + cA3 * accA[3] + cB3;
            out[OUT2 + (size_t)(b * 3 + 1) * HW + pxB] = p3[pxB] + cA3 * accB[3] + cB3;
        } else if (g == 1) {   // oc 4
            out[OUT2 + (size_t)(b * 3 + 2) * HW + pxA] = p4[pxA] + cA4 * accA[0] + cB4;
            out[OUT2 + (size_t)(b * 3 + 2) * HW + pxB] = p4[pxB] + cA4 * accB[0] + cB4;
        }
    }
}

// ---------------------------------------------------------------------------
extern "C" void kernel_launch(void* const* d_in, const int* in_sizes, int n_in,
                              void* d_out, int out_size, void* d_ws, size_t ws_size,
                              hipStream_t stream)
{
    const float* ev = (const float*)d_in[0];
    const float* fr = (const float*)d_in[1];

    char* wb = (char*)d_ws;
    float* coefA    = (float*)(wb + 0);      // 80 f
    float* cBp      = (float*)(wb + 320);    // 80 f
    float* b1f      = (float*)(wb + 640);    // 16 f
    u16*   w1frag   = (u16*) (wb + 768);     // 1536 u16
    u16*   w2frag   = (u16*) (wb + 3840);    // 2560 u16
    float* zbuf     = (float*)(wb + 8960);   // 128 f
    float* partials = (float*)(wb + 10240);  // 16384 f  -> total 75776 B

    bool fast = (ws_size >= 75776);
    int nb   = fast ? 32 : 1;
    int nblk = fast ? 512 : 16;
    k_band<<<dim3(nblk), dim3(1024), 0, stream>>>(ev, fr, nb, partials, zbuf);
    if (fast) k_finalize<<<dim3(16), dim3(256), 0, stream>>>(partials, zbuf);

    k_mlp<<<dim3(1), dim3(64, 16), 0, stream>>>(zbuf,
        (const float*)d_in[12], (const float*)d_in[13], (const float*)d_in[14], (const float*)d_in[15],
        (const float*)d_in[16], (const float*)d_in[17], (const float*)d_in[18], (const float*)d_in[19],
        (const float*)d_in[20],
        (const float*)d_in[2], (const float*)d_in[3], (const float*)d_in[4], (const float*)d_in[5],
        (const float*)d_in[6], (const float*)d_in[7], (const float*)d_in[8], (const float*)d_in[9],
        (const float*)d_in[10], (const float*)d_in[11],
        coefA, cBp, w1frag, w2frag, b1f);

    k_main<<<dim3(16, 32, 16), dim3(256), 0, stream>>>(ev, fr,
        w1frag, w2frag, b1f, coefA, cBp, (float*)d_out);
}